// Round 11
// baseline (685.277 us; speedup 1.0000x reference)
//
#include <hip/hip_runtime.h>
#include <math.h>

// ---------------------------------------------------------------------------
// StageA GNN: encoder -> CSR build -> L x (gateproj, gate, agg, upd+LN) -> head
// R11: (a) enc W1 stored in LDS as packed bf16 pairs -> 2 ds_read_b32/k4
// (was 4) and 48KB LDS -> 3 blocks/CU (12 waves). bf16->f32 unpack is a
// bit-shift (2 VALU ops). (b) gate_kernel is node-grouped via CSR: bb[dst]
// read once per node (205MB -> 13MB L2 traffic/layer); recs shrink to int2.
// ---------------------------------------------------------------------------

typedef unsigned short ushort_t;

__device__ __forceinline__ float bf2f(ushort_t u) {
    return __uint_as_float(((unsigned int)u) << 16);
}
__device__ __forceinline__ ushort_t f2bf(float f) {
    unsigned int x = __float_as_uint(f);
    unsigned int lsb = (x >> 16) & 1u;
    x += 0x7fffu + lsb;                 // round-to-nearest-even
    return (ushort_t)(x >> 16);
}

__device__ __forceinline__ float wave_sum64(float v) {
    #pragma unroll
    for (int o = 32; o > 0; o >>= 1) v += __shfl_xor(v, o, 64);
    return v;
}

// h = relu(relu(x@W1+b1)@W2+b2).  W1 in LDS as bf16 pairs (32KB, k-pair-major
// [p][n]); x in 16-row LDS tiles (16KB). 48KB total -> 3 blocks/CU.
__global__ __launch_bounds__(256) void enc_kernel(
    const float* __restrict__ x, const float* __restrict__ w1,
    const float* __restrict__ b1, const float* __restrict__ w2,
    const float* __restrict__ b2,
    float* __restrict__ h, ushort_t* __restrict__ hb, int N, int C) {
    __shared__ unsigned int wpair[128 * 64];  // 32 KB: (w1[2p][n], w1[2p+1][n])
    __shared__ float xs[16 * 256];            // 16 KB
    const int tid  = threadIdx.x;
    const int lane = tid & 63;
    const int wvid = tid >> 6;        // 0..3
    const float b1l = b1[lane], b2l = b2[lane];
    for (int i = tid; i < 128 * 64; i += 256) {
        int p = i >> 6, n = i & 63;
        unsigned int lo = f2bf(w1[(size_t)(2 * p) * 64 + n]);
        unsigned int hi = f2bf(w1[(size_t)(2 * p + 1) * 64 + n]);
        wpair[i] = lo | (hi << 16);
    }
    const int ntile = (N + 15) >> 4;
    for (int tile = blockIdx.x; tile < ntile; tile += gridDim.x) {
        const int rbase = tile << 4;
        const int rows = min(16, N - rbase);
        __syncthreads();              // previous tile fully consumed
        {   // coalesced stage: rows*64 float4
            const float4* s4 = (const float4*)(x + (size_t)rbase * 256);
            float4* d4 = (float4*)xs;
            for (int i = tid; i < rows * 64; i += 256) d4[i] = s4[i];
        }
        __syncthreads();
        const int r0 = wvid * 4;
        if (r0 + 4 <= rows) {
            const float* xr = xs + r0 * 256;
            float s0 = 0.f, s1 = 0.f, s2 = 0.f, s3 = 0.f;
            #pragma unroll 8
            for (int k4 = 0; k4 < 64; ++k4) {
                unsigned int wp0 = wpair[(k4 * 2) * 64 + lane];
                unsigned int wp1 = wpair[(k4 * 2 + 1) * 64 + lane];
                float wa  = __uint_as_float(wp0 << 16);
                float wbv = __uint_as_float(wp0 & 0xffff0000u);
                float wc  = __uint_as_float(wp1 << 16);
                float wd  = __uint_as_float(wp1 & 0xffff0000u);
                float4 v0 = *(const float4*)(xr + k4 * 4);
                float4 v1 = *(const float4*)(xr + 256 + k4 * 4);
                float4 v2 = *(const float4*)(xr + 512 + k4 * 4);
                float4 v3 = *(const float4*)(xr + 768 + k4 * 4);
                s0 = fmaf(wa, v0.x, s0); s0 = fmaf(wbv, v0.y, s0);
                s0 = fmaf(wc, v0.z, s0); s0 = fmaf(wd, v0.w, s0);
                s1 = fmaf(wa, v1.x, s1); s1 = fmaf(wbv, v1.y, s1);
                s1 = fmaf(wc, v1.z, s1); s1 = fmaf(wd, v1.w, s1);
                s2 = fmaf(wa, v2.x, s2); s2 = fmaf(wbv, v2.y, s2);
                s2 = fmaf(wc, v2.z, s2); s2 = fmaf(wd, v2.w, s2);
                s3 = fmaf(wa, v3.x, s3); s3 = fmaf(wbv, v3.y, s3);
                s3 = fmaf(wc, v3.z, s3); s3 = fmaf(wd, v3.w, s3);
            }
            float t0 = fmaxf(s0 + b1l, 0.f), t1 = fmaxf(s1 + b1l, 0.f);
            float t2 = fmaxf(s2 + b1l, 0.f), t3 = fmaxf(s3 + b1l, 0.f);
            float c0 = 0.f, c1 = 0.f, c2 = 0.f, c3 = 0.f;
            #pragma unroll
            for (int k = 0; k < 64; ++k) {
                float wv = w2[(size_t)k * 64 + lane];
                c0 = fmaf(wv, __shfl(t0, k, 64), c0);
                c1 = fmaf(wv, __shfl(t1, k, 64), c1);
                c2 = fmaf(wv, __shfl(t2, k, 64), c2);
                c3 = fmaf(wv, __shfl(t3, k, 64), c3);
            }
            float h0 = fmaxf(c0 + b2l, 0.f), h1 = fmaxf(c1 + b2l, 0.f);
            float h2 = fmaxf(c2 + b2l, 0.f), h3 = fmaxf(c3 + b2l, 0.f);
            const int r = rbase + r0;
            h[(size_t)(r + 0) * 64 + lane] = h0;
            h[(size_t)(r + 1) * 64 + lane] = h1;
            h[(size_t)(r + 2) * 64 + lane] = h2;
            h[(size_t)(r + 3) * 64 + lane] = h3;
            hb[(size_t)(r + 0) * 64 + lane] = f2bf(h0);
            hb[(size_t)(r + 1) * 64 + lane] = f2bf(h1);
            hb[(size_t)(r + 2) * 64 + lane] = f2bf(h2);
            hb[(size_t)(r + 3) * 64 + lane] = f2bf(h3);
        } else {
            for (int rr = r0; rr < min(r0 + 4, rows); ++rr) {
                const float* xr = xs + rr * 256;
                float acc = 0.f;
                #pragma unroll 8
                for (int k4 = 0; k4 < 64; ++k4) {
                    unsigned int wp0 = wpair[(k4 * 2) * 64 + lane];
                    unsigned int wp1 = wpair[(k4 * 2 + 1) * 64 + lane];
                    float4 v = *(const float4*)(xr + k4 * 4);
                    acc = fmaf(__uint_as_float(wp0 << 16),         v.x, acc);
                    acc = fmaf(__uint_as_float(wp0 & 0xffff0000u), v.y, acc);
                    acc = fmaf(__uint_as_float(wp1 << 16),         v.z, acc);
                    acc = fmaf(__uint_as_float(wp1 & 0xffff0000u), v.w, acc);
                }
                float t = fmaxf(acc + b1l, 0.f);
                float acc2 = 0.f;
                #pragma unroll
                for (int k = 0; k < 64; ++k)
                    acc2 = fmaf(w2[(size_t)k * 64 + lane], __shfl(t, k, 64), acc2);
                float hv = fmaxf(acc2 + b2l, 0.f);
                const int r = rbase + rr;
                h[(size_t)r * 64 + lane] = hv;
                hb[(size_t)r * 64 + lane] = f2bf(hv);
            }
        }
    }
}

// ---- CSR build (once per call, reused by both layers) ----
__global__ __launch_bounds__(256) void hist_kernel(
    const int* __restrict__ dst, int* __restrict__ cnt, int E) {
    for (int e = blockIdx.x * blockDim.x + threadIdx.x; e < E;
         e += gridDim.x * blockDim.x)
        atomicAdd(&cnt[dst[e]], 1);
}

// single-block exclusive scan: cnt[N] -> row_ptr[N+1]
__global__ __launch_bounds__(1024) void scan_kernel(
    const int* __restrict__ cnt, int* __restrict__ row_ptr, int N) {
    __shared__ int sums[1024];
    const int tid = threadIdx.x;
    const int chunk = (N + 1023) / 1024;
    const int beg = tid * chunk;
    const int end = min(beg + chunk, N);
    int s = 0;
    for (int i = beg; i < end; ++i) s += cnt[i];
    sums[tid] = s;
    __syncthreads();
    for (int off = 1; off < 1024; off <<= 1) {
        int v = (tid >= off) ? sums[tid - off] : 0;
        __syncthreads();
        sums[tid] += v;
        __syncthreads();
    }
    int run = (tid == 0) ? 0 : sums[tid - 1];
    for (int i = beg; i < end; ++i) {
        row_ptr[i] = run;
        run += cnt[i];
    }
    if (tid == 1023) row_ptr[N] = sums[1023];
}

// fill dst-grouped records: (src, base_w*sig(rr_s)*sig(rr_d))
__global__ __launch_bounds__(256) void scatter_kernel(
    const int* __restrict__ src, const int* __restrict__ dst,
    const float* __restrict__ base_w, const float* __restrict__ rr,
    const int* __restrict__ row_ptr, int* __restrict__ fill,
    int2* __restrict__ recs, int E) {
    for (int e = blockIdx.x * blockDim.x + threadIdx.x; e < E;
         e += gridDim.x * blockDim.x) {
        int s = src[e], d = dst[e];
        int pos = row_ptr[d] + atomicAdd(&fill[d], 1);
        float rs = 1.f / (1.f + __expf(-rr[s]));
        float rd = 1.f / (1.f + __expf(-rr[d]));
        float c = base_w[e] * rs * rd;
        recs[pos] = make_int2(s, __float_as_int(c));
    }
}

// gate projection: ab = bf16(h@gw1[0:64]+gb1), bbuf = h@gw1[64:128]; k-major
__global__ __launch_bounds__(256) void gateproj_kernel(
    const float* __restrict__ h, const float* __restrict__ gw1,
    const float* __restrict__ gb1, ushort_t* __restrict__ ab,
    float* __restrict__ bbuf, int N) {
    const int lane = threadIdx.x & 63;
    const int wid  = blockIdx.x * (blockDim.x >> 6) + (threadIdx.x >> 6);
    const int nw   = gridDim.x * (blockDim.x >> 6);
    const float gbl = gb1[lane];
    for (int r = wid; r < N; r += nw) {
        float hv = h[(size_t)r * 64 + lane];
        float aa = 0.f, bv = 0.f;
        #pragma unroll
        for (int k = 0; k < 64; ++k) {
            float tv = __shfl(hv, k, 64);
            aa = fmaf(gw1[(size_t)k * 64 + lane], tv, aa);
            bv = fmaf(gw1[(size_t)(64 + k) * 64 + lane], tv, bv);
        }
        ab[(size_t)r * 64 + lane] = f2bf(aa + gbl);
        bbuf[(size_t)r * 64 + lane] = bv;
    }
}

// node-grouped gate: wave-per-node; bb[dst] read ONCE per node; 4 edges in
// flight per wave (16-lane groups), 4-step shfl reduce, a gathered bf16.
__global__ __launch_bounds__(256) void gate_kernel(
    const int* __restrict__ row_ptr, const int2* __restrict__ recs,
    const ushort_t* __restrict__ ab, const float* __restrict__ bb,
    const float* __restrict__ gw2, const float* __restrict__ gb2,
    int2* __restrict__ sw, int N) {
    const int lane = threadIdx.x & 63;
    const int sub  = lane & 15;                       // feature slice id
    const int grp  = lane >> 4;                       // edge slot 0..3
    const float4 gv = ((const float4*)gw2)[sub];
    const float gb = gb2[0];
    const int wid  = blockIdx.x * (blockDim.x >> 6) + (threadIdx.x >> 6);
    const int nw   = gridDim.x * (blockDim.x >> 6);
    for (int n = wid; n < N; n += nw) {
        const int beg = row_ptr[n], end = row_ptr[n + 1];
        const float4 bv = *(const float4*)(bb + (size_t)n * 64 + sub * 4);
        for (int i = beg + grp; i < end; i += 4) {
            int2 r = recs[i];                         // uniform within group
            ushort4 av = ((const ushort4*)(ab + (size_t)r.x * 64))[sub];
            float t = fmaxf(bf2f(av.x) + bv.x, 0.f) * gv.x
                    + fmaxf(bf2f(av.y) + bv.y, 0.f) * gv.y
                    + fmaxf(bf2f(av.z) + bv.z, 0.f) * gv.z
                    + fmaxf(bf2f(av.w) + bv.w, 0.f) * gv.w;
            #pragma unroll
            for (int o = 8; o > 0; o >>= 1) t += __shfl_xor(t, o, 64);
            float w = __int_as_float(r.y) / (1.f + __expf(-(t + gb)));
            if (sub == 0) sw[i] = make_int2(r.x, __float_as_int(w));
        }
    }
}

// pure gather+fma aggregation (wave-per-node): m[n] = sum w*h_bf16[s],
// deg[n] = sum w. No weights, no cross-lane ops -> low VGPR, 8 waves/SIMD.
__global__ __launch_bounds__(256) void agg_kernel(
    const int* __restrict__ row_ptr, const int2* __restrict__ sw,
    const ushort_t* __restrict__ hb_in,
    float* __restrict__ m, float* __restrict__ deg, int N) {
    const int lane = threadIdx.x & 63;
    const int wid  = blockIdx.x * (blockDim.x >> 6) + (threadIdx.x >> 6);
    const int nw   = gridDim.x * (blockDim.x >> 6);
    for (int n = wid; n < N; n += nw) {
        const int beg = row_ptr[n], end = row_ptr[n + 1];
        float macc = 0.f, dacc = 0.f;
        int i = beg;
        for (; i + 8 <= end; i += 8) {
            int2 r0 = sw[i],     r1 = sw[i + 1], r2 = sw[i + 2], r3 = sw[i + 3];
            int2 r4 = sw[i + 4], r5 = sw[i + 5], r6 = sw[i + 6], r7 = sw[i + 7];
            float hv0 = bf2f(hb_in[(size_t)r0.x * 64 + lane]);
            float hv1 = bf2f(hb_in[(size_t)r1.x * 64 + lane]);
            float hv2 = bf2f(hb_in[(size_t)r2.x * 64 + lane]);
            float hv3 = bf2f(hb_in[(size_t)r3.x * 64 + lane]);
            float hv4 = bf2f(hb_in[(size_t)r4.x * 64 + lane]);
            float hv5 = bf2f(hb_in[(size_t)r5.x * 64 + lane]);
            float hv6 = bf2f(hb_in[(size_t)r6.x * 64 + lane]);
            float hv7 = bf2f(hb_in[(size_t)r7.x * 64 + lane]);
            float w0 = __int_as_float(r0.y), w1v = __int_as_float(r1.y);
            float w2v = __int_as_float(r2.y), w3v = __int_as_float(r3.y);
            float w4v = __int_as_float(r4.y), w5v = __int_as_float(r5.y);
            float w6v = __int_as_float(r6.y), w7v = __int_as_float(r7.y);
            macc = fmaf(w0, hv0, macc);  macc = fmaf(w1v, hv1, macc);
            macc = fmaf(w2v, hv2, macc); macc = fmaf(w3v, hv3, macc);
            macc = fmaf(w4v, hv4, macc); macc = fmaf(w5v, hv5, macc);
            macc = fmaf(w6v, hv6, macc); macc = fmaf(w7v, hv7, macc);
            dacc += ((w0 + w1v) + (w2v + w3v)) + ((w4v + w5v) + (w6v + w7v));
        }
        for (; i < end; ++i) {
            int2 r0 = sw[i];
            float hv0 = bf2f(hb_in[(size_t)r0.x * 64 + lane]);
            float w0 = __int_as_float(r0.y);
            macc = fmaf(w0, hv0, macc);
            dacc += w0;
        }
        m[(size_t)n * 64 + lane] = macc;
        if (lane == 0) deg[n] = dacc;
    }
}

// streaming update MLP + LayerNorm: neigh = m/deg; u = relu(neigh@W1+b1)@W2+b2;
// h_out = LN(h_in + u). k-major weights from global (L1-hot, coalesced).
__global__ __launch_bounds__(256) void upd_kernel(
    const float* __restrict__ m, const float* __restrict__ deg,
    const float* __restrict__ h_in,
    const float* __restrict__ w1, const float* __restrict__ b1,
    const float* __restrict__ w2, const float* __restrict__ b2,
    const float* __restrict__ lng, const float* __restrict__ lnb,
    float* __restrict__ h_out, ushort_t* __restrict__ hb_out, int N) {
    const int lane = threadIdx.x & 63;
    const int wid  = blockIdx.x * (blockDim.x >> 6) + (threadIdx.x >> 6);
    const int nw   = gridDim.x * (blockDim.x >> 6);
    const float b1l = b1[lane], b2l = b2[lane];
    const float gl = lng[lane], bl = lnb[lane];
    for (int n = wid; n < N; n += nw) {
        float neigh = m[(size_t)n * 64 + lane] / (deg[n] + 1e-8f);
        float acc = 0.f;
        #pragma unroll
        for (int k = 0; k < 64; ++k) {
            float tv = __shfl(neigh, k, 64);
            acc = fmaf(w1[(size_t)k * 64 + lane], tv, acc);
        }
        float t = fmaxf(acc + b1l, 0.f);
        float acc2 = 0.f;
        #pragma unroll
        for (int k = 0; k < 64; ++k) {
            float tv = __shfl(t, k, 64);
            acc2 = fmaf(w2[(size_t)k * 64 + lane], tv, acc2);
        }
        float pre = h_in[(size_t)n * 64 + lane] + acc2 + b2l;
        float s1 = wave_sum64(pre);
        float s2 = wave_sum64(pre * pre);
        float mean = s1 * (1.0f / 64.0f);
        float var  = s2 * (1.0f / 64.0f) - mean * mean;
        float hn = (pre - mean) * rsqrtf(var + 1e-5f) * gl + bl;
        h_out[(size_t)n * 64 + lane] = hn;
        hb_out[(size_t)n * 64 + lane] = f2bf(hn);
    }
}

// U = softplus(h @ toU_w + toU_b), K=32
__global__ __launch_bounds__(256) void out_kernel(
    const float* __restrict__ h, const float* __restrict__ tw,
    const float* __restrict__ tb, float* __restrict__ U, int N) {
    int gid = blockIdx.x * blockDim.x + threadIdx.x;
    int n = gid >> 5;
    int k = gid & 31;
    if (n >= N) return;
    float acc = tb[k];
    const float* hr = h + (size_t)n * 64;
    #pragma unroll 8
    for (int j = 0; j < 64; ++j) acc = fmaf(hr[j], tw[j * 32 + k], acc);
    float sp = acc > 0.f ? acc + log1pf(__expf(-acc)) : log1pf(__expf(acc));
    U[(size_t)n * 32 + k] = sp;
}

extern "C" void kernel_launch(void* const* d_in, const int* in_sizes, int n_in,
                              void* d_out, int out_size, void* d_ws, size_t ws_size,
                              hipStream_t stream) {
    const float* x       = (const float*)d_in[0];
    const int*   src     = (const int*)d_in[1];
    const int*   dst     = (const int*)d_in[2];
    const float* base_w  = (const float*)d_in[3];
    const float* enc_w1  = (const float*)d_in[4];
    const float* enc_b1  = (const float*)d_in[5];
    const float* enc_w2  = (const float*)d_in[6];
    const float* enc_b2  = (const float*)d_in[7];
    const float* gate_w1 = (const float*)d_in[8];
    const float* gate_b1 = (const float*)d_in[9];
    const float* gate_w2 = (const float*)d_in[10];
    const float* gate_b2 = (const float*)d_in[11];
    const float* upd_w1  = (const float*)d_in[12];
    const float* upd_b1  = (const float*)d_in[13];
    const float* upd_w2  = (const float*)d_in[14];
    const float* upd_b2  = (const float*)d_in[15];
    const float* ln_g    = (const float*)d_in[16];
    const float* ln_b    = (const float*)d_in[17];
    const float* rho_raw = (const float*)d_in[18];
    const float* toU_w   = (const float*)d_in[19];
    const float* toU_b   = (const float*)d_in[20];

    const int N = in_sizes[18];          // 50000
    const int C = in_sizes[0] / N;       // 256
    const int E = in_sizes[1];           // 800000
    const int L = 2;

    // workspace layout (float units), sections padded to 16B alignment
    float* ws  = (float*)d_ws;
    size_t off = 0;
    float* h0  = ws + off; off += (size_t)N * 64;
    float* h1  = ws + off; off += (size_t)N * 64;
    ushort_t* hb0 = (ushort_t*)(ws + off); off += (size_t)N * 32;
    ushort_t* hb1 = (ushort_t*)(ws + off); off += (size_t)N * 32;
    ushort_t* ab  = (ushort_t*)(ws + off); off += (size_t)N * 32;
    float* bb  = ws + off; off += (size_t)N * 64;
    float* m   = ws + off; off += (size_t)N * 64;
    float* deg = ws + off; off += (size_t)((N + 3) & ~3);
    int* row_ptr = (int*)(ws + off); off += (size_t)((N + 1 + 3) & ~3);
    int* cnt     = (int*)(ws + off); off += (size_t)((N + 3) & ~3);
    int2* recs   = (int2*)(ws + off); off += (size_t)E * 2;   // (s,c)
    int2* sw     = (int2*)(ws + off); off += (size_t)E * 2;   // (s,w)

    enc_kernel<<<1024, 256, 0, stream>>>(x, enc_w1, enc_b1, enc_w2, enc_b2,
                                         h0, hb0, N, C);

    // CSR build (dst-sorted edge records); rho folded into scatter
    hipMemsetAsync(cnt, 0, (size_t)N * sizeof(int), stream);
    hist_kernel<<<(E + 255) / 256, 256, 0, stream>>>(dst, cnt, E);
    scan_kernel<<<1, 1024, 0, stream>>>(cnt, row_ptr, N);
    hipMemsetAsync(cnt, 0, (size_t)N * sizeof(int), stream);
    scatter_kernel<<<(E + 255) / 256, 256, 0, stream>>>(src, dst, base_w, rho_raw,
                                                        row_ptr, cnt, recs, E);

    float* h_cur = h0;  ushort_t* hb_cur = hb0;
    float* h_nxt = h1;  ushort_t* hb_nxt = hb1;
    for (int l = 0; l < L; ++l) {
        gateproj_kernel<<<1024, 256, 0, stream>>>(h_cur, gate_w1, gate_b1,
                                                  ab, bb, N);
        gate_kernel<<<2048, 256, 0, stream>>>(row_ptr, recs, ab, bb,
                                              gate_w2, gate_b2, sw, N);
        agg_kernel<<<2048, 256, 0, stream>>>(row_ptr, sw, hb_cur, m, deg, N);
        upd_kernel<<<1024, 256, 0, stream>>>(
            m, deg, h_cur,
            upd_w1 + (size_t)l * 4096, upd_b1 + l * 64,
            upd_w2 + (size_t)l * 4096, upd_b2 + l * 64,
            ln_g + l * 64, ln_b + l * 64, h_nxt, hb_nxt, N);
        float* tf = h_cur; h_cur = h_nxt; h_nxt = tf;
        ushort_t* tb2 = hb_cur; hb_cur = hb_nxt; hb_nxt = tb2;
    }

    out_kernel<<<((N * 32) + 255) / 256, 256, 0, stream>>>(h_cur, toU_w, toU_b,
                                                           (float*)d_out, N);
}

// Round 12
// 593.297 us; speedup vs baseline: 1.1550x; 1.1550x over previous
//
#include <hip/hip_runtime.h>
#include <math.h>

// ---------------------------------------------------------------------------
// StageA GNN: encoder -> CSR build -> L x (gateproj, gateagg, upd+LN) -> head
// R12: fuse gate+agg with a co-designed layout: gateproj packs per-node
// [a_bf16|h_bf16] 256B rows (ahb) so the fused kernel's two gathers per edge
// hit ONE cache line; 16-lane group per edge, 4-step reduce, 2-way unroll
// (8 edges in flight/wave), no LDS, cross-group combine, coalesced m write.
// Kills the sw round-trip and a full edge pass. enc = proven R10 version.
// ---------------------------------------------------------------------------

typedef unsigned short ushort_t;

__device__ __forceinline__ float bf2f(ushort_t u) {
    return __uint_as_float(((unsigned int)u) << 16);
}
__device__ __forceinline__ ushort_t f2bf(float f) {
    unsigned int x = __float_as_uint(f);
    unsigned int lsb = (x >> 16) & 1u;
    x += 0x7fffu + lsb;                 // round-to-nearest-even
    return (ushort_t)(x >> 16);
}

__device__ __forceinline__ float wave_sum64(float v) {
    #pragma unroll
    for (int o = 32; o > 0; o >>= 1) v += __shfl_xor(v, o, 64);
    return v;
}

// h = relu(relu(x@W1+b1)@W2+b2).  W1 in LDS (64KB, k-major); x in 16-row
// LDS tiles (16KB, coalesced stage). R10 version (proven 124us).
__global__ __launch_bounds__(256) void enc_kernel(
    const float* __restrict__ x, const float* __restrict__ w1,
    const float* __restrict__ b1, const float* __restrict__ w2,
    const float* __restrict__ b2,
    float* __restrict__ h, int N, int C) {
    __shared__ float ws1[256 * 64];   // 64 KB
    __shared__ float xs[16 * 256];    // 16 KB
    const int tid  = threadIdx.x;
    const int lane = tid & 63;
    const int wvid = tid >> 6;        // 0..3
    const float b1l = b1[lane], b2l = b2[lane];
    for (int i = tid; i < 256 * 64; i += 256) ws1[i] = w1[i];
    const int ntile = (N + 15) >> 4;
    for (int tile = blockIdx.x; tile < ntile; tile += gridDim.x) {
        const int rbase = tile << 4;
        const int rows = min(16, N - rbase);
        __syncthreads();              // previous tile fully consumed
        {   // coalesced stage: rows*64 float4
            const float4* s4 = (const float4*)(x + (size_t)rbase * 256);
            float4* d4 = (float4*)xs;
            for (int i = tid; i < rows * 64; i += 256) d4[i] = s4[i];
        }
        __syncthreads();
        const int r0 = wvid * 4;
        if (r0 + 4 <= rows) {
            const float* xr = xs + r0 * 256;
            float s0 = 0.f, s1 = 0.f, s2 = 0.f, s3 = 0.f;
            #pragma unroll 8
            for (int k4 = 0; k4 < 64; ++k4) {
                const float* wp = ws1 + k4 * 256 + lane;
                float wa = wp[0], wbv = wp[64], wc = wp[128], wd = wp[192];
                float4 v0 = *(const float4*)(xr + k4 * 4);
                float4 v1 = *(const float4*)(xr + 256 + k4 * 4);
                float4 v2 = *(const float4*)(xr + 512 + k4 * 4);
                float4 v3 = *(const float4*)(xr + 768 + k4 * 4);
                s0 = fmaf(wa, v0.x, s0); s0 = fmaf(wbv, v0.y, s0);
                s0 = fmaf(wc, v0.z, s0); s0 = fmaf(wd, v0.w, s0);
                s1 = fmaf(wa, v1.x, s1); s1 = fmaf(wbv, v1.y, s1);
                s1 = fmaf(wc, v1.z, s1); s1 = fmaf(wd, v1.w, s1);
                s2 = fmaf(wa, v2.x, s2); s2 = fmaf(wbv, v2.y, s2);
                s2 = fmaf(wc, v2.z, s2); s2 = fmaf(wd, v2.w, s2);
                s3 = fmaf(wa, v3.x, s3); s3 = fmaf(wbv, v3.y, s3);
                s3 = fmaf(wc, v3.z, s3); s3 = fmaf(wd, v3.w, s3);
            }
            float t0 = fmaxf(s0 + b1l, 0.f), t1 = fmaxf(s1 + b1l, 0.f);
            float t2 = fmaxf(s2 + b1l, 0.f), t3 = fmaxf(s3 + b1l, 0.f);
            float c0 = 0.f, c1 = 0.f, c2 = 0.f, c3 = 0.f;
            #pragma unroll
            for (int k = 0; k < 64; ++k) {
                float wv = w2[(size_t)k * 64 + lane];
                c0 = fmaf(wv, __shfl(t0, k, 64), c0);
                c1 = fmaf(wv, __shfl(t1, k, 64), c1);
                c2 = fmaf(wv, __shfl(t2, k, 64), c2);
                c3 = fmaf(wv, __shfl(t3, k, 64), c3);
            }
            float h0 = fmaxf(c0 + b2l, 0.f), h1 = fmaxf(c1 + b2l, 0.f);
            float h2 = fmaxf(c2 + b2l, 0.f), h3 = fmaxf(c3 + b2l, 0.f);
            const int r = rbase + r0;
            h[(size_t)(r + 0) * 64 + lane] = h0;
            h[(size_t)(r + 1) * 64 + lane] = h1;
            h[(size_t)(r + 2) * 64 + lane] = h2;
            h[(size_t)(r + 3) * 64 + lane] = h3;
        } else {
            for (int rr = r0; rr < min(r0 + 4, rows); ++rr) {
                const float* xr = xs + rr * 256;
                float acc = 0.f;
                #pragma unroll 8
                for (int k4 = 0; k4 < 64; ++k4) {
                    const float* wp = ws1 + k4 * 256 + lane;
                    float4 v = *(const float4*)(xr + k4 * 4);
                    acc = fmaf(wp[0],   v.x, acc);
                    acc = fmaf(wp[64],  v.y, acc);
                    acc = fmaf(wp[128], v.z, acc);
                    acc = fmaf(wp[192], v.w, acc);
                }
                float t = fmaxf(acc + b1l, 0.f);
                float acc2 = 0.f;
                #pragma unroll
                for (int k = 0; k < 64; ++k)
                    acc2 = fmaf(w2[(size_t)k * 64 + lane], __shfl(t, k, 64), acc2);
                float hv = fmaxf(acc2 + b2l, 0.f);
                const int r = rbase + rr;
                h[(size_t)r * 64 + lane] = hv;
            }
        }
    }
}

// ---- CSR build (once per call, reused by both layers) ----
__global__ __launch_bounds__(256) void hist_kernel(
    const int* __restrict__ dst, int* __restrict__ cnt, int E) {
    for (int e = blockIdx.x * blockDim.x + threadIdx.x; e < E;
         e += gridDim.x * blockDim.x)
        atomicAdd(&cnt[dst[e]], 1);
}

// single-block exclusive scan: cnt[N] -> row_ptr[N+1]
__global__ __launch_bounds__(1024) void scan_kernel(
    const int* __restrict__ cnt, int* __restrict__ row_ptr, int N) {
    __shared__ int sums[1024];
    const int tid = threadIdx.x;
    const int chunk = (N + 1023) / 1024;
    const int beg = tid * chunk;
    const int end = min(beg + chunk, N);
    int s = 0;
    for (int i = beg; i < end; ++i) s += cnt[i];
    sums[tid] = s;
    __syncthreads();
    for (int off = 1; off < 1024; off <<= 1) {
        int v = (tid >= off) ? sums[tid - off] : 0;
        __syncthreads();
        sums[tid] += v;
        __syncthreads();
    }
    int run = (tid == 0) ? 0 : sums[tid - 1];
    for (int i = beg; i < end; ++i) {
        row_ptr[i] = run;
        run += cnt[i];
    }
    if (tid == 1023) row_ptr[N] = sums[1023];
}

// fill dst-grouped records: (src, base_w*sig(rr_s)*sig(rr_d))
__global__ __launch_bounds__(256) void scatter_kernel(
    const int* __restrict__ src, const int* __restrict__ dst,
    const float* __restrict__ base_w, const float* __restrict__ rr,
    const int* __restrict__ row_ptr, int* __restrict__ fill,
    int2* __restrict__ recs, int E) {
    for (int e = blockIdx.x * blockDim.x + threadIdx.x; e < E;
         e += gridDim.x * blockDim.x) {
        int s = src[e], d = dst[e];
        int pos = row_ptr[d] + atomicAdd(&fill[d], 1);
        float rs = 1.f / (1.f + __expf(-rr[s]));
        float rd = 1.f / (1.f + __expf(-rr[d]));
        float c = base_w[e] * rs * rd;
        recs[pos] = make_int2(s, __float_as_int(c));
    }
}

// gate projection + pack: ahb[r] = [ bf16(h@gw1a+gb1) | bf16(h) ] (256B row),
// bbuf = h@gw1b.  k-major gw1 reads (coalesced, L1-hot).
__global__ __launch_bounds__(256) void gateproj_kernel(
    const float* __restrict__ h, const float* __restrict__ gw1,
    const float* __restrict__ gb1, ushort_t* __restrict__ ahb,
    float* __restrict__ bbuf, int N) {
    const int lane = threadIdx.x & 63;
    const int wid  = blockIdx.x * (blockDim.x >> 6) + (threadIdx.x >> 6);
    const int nw   = gridDim.x * (blockDim.x >> 6);
    const float gbl = gb1[lane];
    for (int r = wid; r < N; r += nw) {
        float hv = h[(size_t)r * 64 + lane];
        float aa = 0.f, bv = 0.f;
        #pragma unroll
        for (int k = 0; k < 64; ++k) {
            float tv = __shfl(hv, k, 64);
            aa = fmaf(gw1[(size_t)k * 64 + lane], tv, aa);
            bv = fmaf(gw1[(size_t)(64 + k) * 64 + lane], tv, bv);
        }
        ahb[(size_t)r * 128 + lane]      = f2bf(aa + gbl);
        ahb[(size_t)r * 128 + 64 + lane] = f2bf(hv);
        bbuf[(size_t)r * 64 + lane]      = bv;
    }
}

// fused gate + aggregation: wave-per-node, 16-lane group per edge, 2-way
// unroll (8 edges in flight/wave). Per edge: gather a+h from ONE 256B row,
// 4-step group reduce, sigmoid, fma into per-group float4 accumulators.
// Cross-group combine, coalesced float4 m write. No LDS.
__global__ __launch_bounds__(256) void gateagg_kernel(
    const int* __restrict__ row_ptr, const int2* __restrict__ recs,
    const ushort_t* __restrict__ ahb, const float* __restrict__ bb,
    const float* __restrict__ gw2, const float* __restrict__ gb2,
    float* __restrict__ m, float* __restrict__ deg, int N) {
    const int lane = threadIdx.x & 63;
    const int sub  = lane & 15;
    const int grp  = lane >> 4;
    const float4 gv = ((const float4*)gw2)[sub];
    const float gb = gb2[0];
    const int wid  = blockIdx.x * (blockDim.x >> 6) + (threadIdx.x >> 6);
    const int nw   = gridDim.x * (blockDim.x >> 6);
    for (int n = wid; n < N; n += nw) {
        const int beg = row_ptr[n], end = row_ptr[n + 1];
        const float4 bv = *(const float4*)(bb + (size_t)n * 64 + sub * 4);
        float m0 = 0.f, m1 = 0.f, m2 = 0.f, m3 = 0.f, dacc = 0.f;
        int i = beg + grp;
        for (; i + 4 < end; i += 8) {              // two edges per iteration
            int2 rA = recs[i];
            int2 rB = recs[i + 4];
            const ushort_t* rowA = ahb + (size_t)rA.x * 128;
            const ushort_t* rowB = ahb + (size_t)rB.x * 128;
            ushort4 avA = *(const ushort4*)(rowA + sub * 4);
            ushort4 hvA = *(const ushort4*)(rowA + 64 + sub * 4);
            ushort4 avB = *(const ushort4*)(rowB + sub * 4);
            ushort4 hvB = *(const ushort4*)(rowB + 64 + sub * 4);
            float tA = fmaxf(bf2f(avA.x) + bv.x, 0.f) * gv.x
                     + fmaxf(bf2f(avA.y) + bv.y, 0.f) * gv.y
                     + fmaxf(bf2f(avA.z) + bv.z, 0.f) * gv.z
                     + fmaxf(bf2f(avA.w) + bv.w, 0.f) * gv.w;
            float tB = fmaxf(bf2f(avB.x) + bv.x, 0.f) * gv.x
                     + fmaxf(bf2f(avB.y) + bv.y, 0.f) * gv.y
                     + fmaxf(bf2f(avB.z) + bv.z, 0.f) * gv.z
                     + fmaxf(bf2f(avB.w) + bv.w, 0.f) * gv.w;
            #pragma unroll
            for (int o = 8; o > 0; o >>= 1) {
                tA += __shfl_xor(tA, o, 64);
                tB += __shfl_xor(tB, o, 64);
            }
            float wA = __int_as_float(rA.y) / (1.f + __expf(-(tA + gb)));
            float wB = __int_as_float(rB.y) / (1.f + __expf(-(tB + gb)));
            m0 = fmaf(wA, bf2f(hvA.x), m0); m0 = fmaf(wB, bf2f(hvB.x), m0);
            m1 = fmaf(wA, bf2f(hvA.y), m1); m1 = fmaf(wB, bf2f(hvB.y), m1);
            m2 = fmaf(wA, bf2f(hvA.z), m2); m2 = fmaf(wB, bf2f(hvB.z), m2);
            m3 = fmaf(wA, bf2f(hvA.w), m3); m3 = fmaf(wB, bf2f(hvB.w), m3);
            dacc += wA + wB;
        }
        if (i < end) {                             // tail edge for this group
            int2 r = recs[i];
            const ushort_t* row = ahb + (size_t)r.x * 128;
            ushort4 av = *(const ushort4*)(row + sub * 4);
            ushort4 hv = *(const ushort4*)(row + 64 + sub * 4);
            float t = fmaxf(bf2f(av.x) + bv.x, 0.f) * gv.x
                    + fmaxf(bf2f(av.y) + bv.y, 0.f) * gv.y
                    + fmaxf(bf2f(av.z) + bv.z, 0.f) * gv.z
                    + fmaxf(bf2f(av.w) + bv.w, 0.f) * gv.w;
            #pragma unroll
            for (int o = 8; o > 0; o >>= 1) t += __shfl_xor(t, o, 64);
            float w = __int_as_float(r.y) / (1.f + __expf(-(t + gb)));
            m0 = fmaf(w, bf2f(hv.x), m0);
            m1 = fmaf(w, bf2f(hv.y), m1);
            m2 = fmaf(w, bf2f(hv.z), m2);
            m3 = fmaf(w, bf2f(hv.w), m3);
            dacc += w;
        }
        // combine the 4 groups (xor 16, 32)
        #pragma unroll
        for (int o = 16; o < 64; o <<= 1) {
            m0 += __shfl_xor(m0, o, 64);
            m1 += __shfl_xor(m1, o, 64);
            m2 += __shfl_xor(m2, o, 64);
            m3 += __shfl_xor(m3, o, 64);
            dacc += __shfl_xor(dacc, o, 64);
        }
        if (lane < 16) {
            *(float4*)(m + (size_t)n * 64 + sub * 4) = make_float4(m0, m1, m2, m3);
            if (lane == 0) deg[n] = dacc;
        }
    }
}

// streaming update MLP + LayerNorm: neigh = m/deg; u = relu(neigh@W1+b1)@W2+b2;
// h_out = LN(h_in + u). k-major weights from global (L1-hot, coalesced).
__global__ __launch_bounds__(256) void upd_kernel(
    const float* __restrict__ m, const float* __restrict__ deg,
    const float* __restrict__ h_in,
    const float* __restrict__ w1, const float* __restrict__ b1,
    const float* __restrict__ w2, const float* __restrict__ b2,
    const float* __restrict__ lng, const float* __restrict__ lnb,
    float* __restrict__ h_out, int N) {
    const int lane = threadIdx.x & 63;
    const int wid  = blockIdx.x * (blockDim.x >> 6) + (threadIdx.x >> 6);
    const int nw   = gridDim.x * (blockDim.x >> 6);
    const float b1l = b1[lane], b2l = b2[lane];
    const float gl = lng[lane], bl = lnb[lane];
    for (int n = wid; n < N; n += nw) {
        float neigh = m[(size_t)n * 64 + lane] / (deg[n] + 1e-8f);
        float acc = 0.f;
        #pragma unroll
        for (int k = 0; k < 64; ++k) {
            float tv = __shfl(neigh, k, 64);
            acc = fmaf(w1[(size_t)k * 64 + lane], tv, acc);
        }
        float t = fmaxf(acc + b1l, 0.f);
        float acc2 = 0.f;
        #pragma unroll
        for (int k = 0; k < 64; ++k) {
            float tv = __shfl(t, k, 64);
            acc2 = fmaf(w2[(size_t)k * 64 + lane], tv, acc2);
        }
        float pre = h_in[(size_t)n * 64 + lane] + acc2 + b2l;
        float s1 = wave_sum64(pre);
        float s2 = wave_sum64(pre * pre);
        float mean = s1 * (1.0f / 64.0f);
        float var  = s2 * (1.0f / 64.0f) - mean * mean;
        float hn = (pre - mean) * rsqrtf(var + 1e-5f) * gl + bl;
        h_out[(size_t)n * 64 + lane] = hn;
    }
}

// U = softplus(h @ toU_w + toU_b), K=32
__global__ __launch_bounds__(256) void out_kernel(
    const float* __restrict__ h, const float* __restrict__ tw,
    const float* __restrict__ tb, float* __restrict__ U, int N) {
    int gid = blockIdx.x * blockDim.x + threadIdx.x;
    int n = gid >> 5;
    int k = gid & 31;
    if (n >= N) return;
    float acc = tb[k];
    const float* hr = h + (size_t)n * 64;
    #pragma unroll 8
    for (int j = 0; j < 64; ++j) acc = fmaf(hr[j], tw[j * 32 + k], acc);
    float sp = acc > 0.f ? acc + log1pf(__expf(-acc)) : log1pf(__expf(acc));
    U[(size_t)n * 32 + k] = sp;
}

extern "C" void kernel_launch(void* const* d_in, const int* in_sizes, int n_in,
                              void* d_out, int out_size, void* d_ws, size_t ws_size,
                              hipStream_t stream) {
    const float* x       = (const float*)d_in[0];
    const int*   src     = (const int*)d_in[1];
    const int*   dst     = (const int*)d_in[2];
    const float* base_w  = (const float*)d_in[3];
    const float* enc_w1  = (const float*)d_in[4];
    const float* enc_b1  = (const float*)d_in[5];
    const float* enc_w2  = (const float*)d_in[6];
    const float* enc_b2  = (const float*)d_in[7];
    const float* gate_w1 = (const float*)d_in[8];
    const float* gate_b1 = (const float*)d_in[9];
    const float* gate_w2 = (const float*)d_in[10];
    const float* gate_b2 = (const float*)d_in[11];
    const float* upd_w1  = (const float*)d_in[12];
    const float* upd_b1  = (const float*)d_in[13];
    const float* upd_w2  = (const float*)d_in[14];
    const float* upd_b2  = (const float*)d_in[15];
    const float* ln_g    = (const float*)d_in[16];
    const float* ln_b    = (const float*)d_in[17];
    const float* rho_raw = (const float*)d_in[18];
    const float* toU_w   = (const float*)d_in[19];
    const float* toU_b   = (const float*)d_in[20];

    const int N = in_sizes[18];          // 50000
    const int C = in_sizes[0] / N;       // 256
    const int E = in_sizes[1];           // 800000
    const int L = 2;

    // workspace layout (float units), sections padded to 16B alignment
    float* ws  = (float*)d_ws;
    size_t off = 0;
    float* h0  = ws + off; off += (size_t)N * 64;
    float* h1  = ws + off; off += (size_t)N * 64;
    ushort_t* ahb = (ushort_t*)(ws + off); off += (size_t)N * 64;  // N*128 ushort
    float* bb  = ws + off; off += (size_t)N * 64;
    float* m   = ws + off; off += (size_t)N * 64;
    float* deg = ws + off; off += (size_t)((N + 3) & ~3);
    int* row_ptr = (int*)(ws + off); off += (size_t)((N + 1 + 3) & ~3);
    int* cnt     = (int*)(ws + off); off += (size_t)((N + 3) & ~3);
    int2* recs   = (int2*)(ws + off); off += (size_t)E * 2;   // (s,c)

    enc_kernel<<<1024, 256, 0, stream>>>(x, enc_w1, enc_b1, enc_w2, enc_b2,
                                         h0, N, C);

    // CSR build (dst-sorted edge records); rho folded into scatter
    hipMemsetAsync(cnt, 0, (size_t)N * sizeof(int), stream);
    hist_kernel<<<(E + 255) / 256, 256, 0, stream>>>(dst, cnt, E);
    scan_kernel<<<1, 1024, 0, stream>>>(cnt, row_ptr, N);
    hipMemsetAsync(cnt, 0, (size_t)N * sizeof(int), stream);
    scatter_kernel<<<(E + 255) / 256, 256, 0, stream>>>(src, dst, base_w, rho_raw,
                                                        row_ptr, cnt, recs, E);

    float* h_cur = h0;
    float* h_nxt = h1;
    for (int l = 0; l < L; ++l) {
        gateproj_kernel<<<1024, 256, 0, stream>>>(h_cur, gate_w1, gate_b1,
                                                  ahb, bb, N);
        gateagg_kernel<<<2048, 256, 0, stream>>>(row_ptr, recs, ahb, bb,
                                                 gate_w2, gate_b2, m, deg, N);
        upd_kernel<<<1024, 256, 0, stream>>>(
            m, deg, h_cur,
            upd_w1 + (size_t)l * 4096, upd_b1 + l * 64,
            upd_w2 + (size_t)l * 4096, upd_b2 + l * 64,
            ln_g + l * 64, ln_b + l * 64, h_nxt, N);
        float* tf = h_cur; h_cur = h_nxt; h_nxt = tf;
    }

    out_kernel<<<((N * 32) + 255) / 256, 256, 0, stream>>>(h_cur, toU_w, toU_b,
                                                           (float*)d_out, N);
}

// Round 13
// 533.093 us; speedup vs baseline: 1.2855x; 1.1129x over previous
//
#include <hip/hip_runtime.h>
#include <math.h>

// ---------------------------------------------------------------------------
// StageA GNN: pack -> MFMA-encoder -> CSR -> L x (gateproj, gateagg, upd) -> head
// R13: encoder rewritten on matrix cores (mfma_f32_16x16x32_bf16).
// W1/W2 pre-packed into B-fragment order (global, L1-hot, 16B/lane coalesced);
// x staged bf16 in LDS (row pad 8 for 16B-aligned fragment reads); per-wave
// 16-row tile: 8x4 MFMAs (GEMM1) -> relu t in LDS -> 2x4 MFMAs (GEMM2).
// Fragment maps per m89-verified layout. Rest of pipeline = proven R12.
// ---------------------------------------------------------------------------

typedef unsigned short ushort_t;
typedef __attribute__((ext_vector_type(8))) short bf16x8;
typedef __attribute__((ext_vector_type(4))) float f32x4;

__device__ __forceinline__ float bf2f(ushort_t u) {
    return __uint_as_float(((unsigned int)u) << 16);
}
__device__ __forceinline__ ushort_t f2bf(float f) {
    unsigned int x = __float_as_uint(f);
    unsigned int lsb = (x >> 16) & 1u;
    x += 0x7fffu + lsb;                 // round-to-nearest-even
    return (ushort_t)(x >> 16);
}

__device__ __forceinline__ float wave_sum64(float v) {
    #pragma unroll
    for (int o = 32; o > 0; o >>= 1) v += __shfl_xor(v, o, 64);
    return v;
}

// pack W1 (256x64) / W2 (64x64) into MFMA B-fragment order, bf16.
// w1f[nt][kb][lane][i]: k = kb*32 + (lane>>4)*8 + i, n = nt*16 + (lane&15).
__global__ __launch_bounds__(256) void pack_kernel(
    const float* __restrict__ w1, const float* __restrict__ w2,
    ushort_t* __restrict__ w1f, ushort_t* __restrict__ w2f) {
    int t = blockIdx.x * 256 + threadIdx.x;
    if (t < 4 * 8 * 64 * 8) {
        int i = t & 7, l = (t >> 3) & 63, kb = (t >> 9) & 7, nt = t >> 12;
        int k = kb * 32 + (l >> 4) * 8 + i;
        int n = nt * 16 + (l & 15);
        w1f[t] = f2bf(w1[(size_t)k * 64 + n]);
    }
    if (t < 4 * 2 * 64 * 8) {
        int i = t & 7, l = (t >> 3) & 63, kb = (t >> 9) & 1, nt = t >> 10;
        int k = kb * 32 + (l >> 4) * 8 + i;
        int n = nt * 16 + (l & 15);
        w2f[t] = f2bf(w2[(size_t)k * 64 + n]);
    }
}

// MFMA encoder: h = relu(relu(x@W1+b1)@W2+b2), block = 64 rows, wave = 16.
__global__ __launch_bounds__(256) void enc_kernel(
    const float* __restrict__ x, const ushort_t* __restrict__ w1f,
    const float* __restrict__ b1, const ushort_t* __restrict__ w2f,
    const float* __restrict__ b2, float* __restrict__ h, int N) {
    __shared__ ushort_t xls[4][16][264];   // 33792 B (pad 8 -> 16B-aligned rows)
    __shared__ ushort_t tls[4][16][72];    // 9216 B
    const int tid  = threadIdx.x;
    const int lane = tid & 63;
    const int w    = tid >> 6;
    const int m    = lane & 15;
    const int g    = lane >> 4;
    const int rbase = blockIdx.x * 64;
    // stage x tile fp32 -> bf16 (coalesced 8B/lane reads)
    for (int p = tid; p < 64 * 128; p += 256) {
        int row = p >> 7, kp = p & 127;
        int grow = rbase + row;
        float2 v = (grow < N) ? *(const float2*)(x + (size_t)grow * 256 + kp * 2)
                              : make_float2(0.f, 0.f);
        unsigned int pk = (unsigned int)f2bf(v.x) | ((unsigned int)f2bf(v.y) << 16);
        *(unsigned int*)&xls[row >> 4][row & 15][kp * 2] = pk;
    }
    __syncthreads();
    // GEMM1: t(16x64) = x_tile(16x256) @ W1(256x64)
    f32x4 acc[4] = {{0,0,0,0},{0,0,0,0},{0,0,0,0},{0,0,0,0}};
    #pragma unroll
    for (int kb = 0; kb < 8; ++kb) {
        bf16x8 a = *(const bf16x8*)&xls[w][m][kb * 32 + g * 8];
        #pragma unroll
        for (int nt = 0; nt < 4; ++nt) {
            bf16x8 b = *(const bf16x8*)(w1f + (((size_t)nt * 8 + kb) * 64 + lane) * 8);
            acc[nt] = __builtin_amdgcn_mfma_f32_16x16x32_bf16(a, b, acc[nt], 0, 0, 0);
        }
    }
    // relu + bf16 t into per-wave LDS tile (no barrier needed: within-wave)
    #pragma unroll
    for (int nt = 0; nt < 4; ++nt) {
        float bb1 = b1[nt * 16 + m];
        #pragma unroll
        for (int r = 0; r < 4; ++r) {
            float tv = fmaxf(acc[nt][r] + bb1, 0.f);
            tls[w][g * 4 + r][nt * 16 + m] = f2bf(tv);
        }
    }
    // GEMM2: h(16x64) = t(16x64) @ W2(64x64)
    f32x4 acc2[4] = {{0,0,0,0},{0,0,0,0},{0,0,0,0},{0,0,0,0}};
    #pragma unroll
    for (int kb = 0; kb < 2; ++kb) {
        bf16x8 a2 = *(const bf16x8*)&tls[w][m][kb * 32 + g * 8];
        #pragma unroll
        for (int nt = 0; nt < 4; ++nt) {
            bf16x8 b = *(const bf16x8*)(w2f + (((size_t)nt * 2 + kb) * 64 + lane) * 8);
            acc2[nt] = __builtin_amdgcn_mfma_f32_16x16x32_bf16(a2, b, acc2[nt], 0, 0, 0);
        }
    }
    #pragma unroll
    for (int nt = 0; nt < 4; ++nt) {
        float bb2 = b2[nt * 16 + m];
        #pragma unroll
        for (int r = 0; r < 4; ++r) {
            int grow = rbase + w * 16 + g * 4 + r;
            if (grow < N)
                h[(size_t)grow * 64 + nt * 16 + m] = fmaxf(acc2[nt][r] + bb2, 0.f);
        }
    }
}

// ---- CSR build (once per call, reused by both layers) ----
__global__ __launch_bounds__(256) void hist_kernel(
    const int* __restrict__ dst, int* __restrict__ cnt, int E) {
    for (int e = blockIdx.x * blockDim.x + threadIdx.x; e < E;
         e += gridDim.x * blockDim.x)
        atomicAdd(&cnt[dst[e]], 1);
}

// single-block exclusive scan: cnt[N] -> row_ptr[N+1]
__global__ __launch_bounds__(1024) void scan_kernel(
    const int* __restrict__ cnt, int* __restrict__ row_ptr, int N) {
    __shared__ int sums[1024];
    const int tid = threadIdx.x;
    const int chunk = (N + 1023) / 1024;
    const int beg = tid * chunk;
    const int end = min(beg + chunk, N);
    int s = 0;
    for (int i = beg; i < end; ++i) s += cnt[i];
    sums[tid] = s;
    __syncthreads();
    for (int off = 1; off < 1024; off <<= 1) {
        int v = (tid >= off) ? sums[tid - off] : 0;
        __syncthreads();
        sums[tid] += v;
        __syncthreads();
    }
    int run = (tid == 0) ? 0 : sums[tid - 1];
    for (int i = beg; i < end; ++i) {
        row_ptr[i] = run;
        run += cnt[i];
    }
    if (tid == 1023) row_ptr[N] = sums[1023];
}

// fill dst-grouped records: (src, base_w*sig(rr_s)*sig(rr_d))
__global__ __launch_bounds__(256) void scatter_kernel(
    const int* __restrict__ src, const int* __restrict__ dst,
    const float* __restrict__ base_w, const float* __restrict__ rr,
    const int* __restrict__ row_ptr, int* __restrict__ fill,
    int2* __restrict__ recs, int E) {
    for (int e = blockIdx.x * blockDim.x + threadIdx.x; e < E;
         e += gridDim.x * blockDim.x) {
        int s = src[e], d = dst[e];
        int pos = row_ptr[d] + atomicAdd(&fill[d], 1);
        float rs = 1.f / (1.f + __expf(-rr[s]));
        float rd = 1.f / (1.f + __expf(-rr[d]));
        float c = base_w[e] * rs * rd;
        recs[pos] = make_int2(s, __float_as_int(c));
    }
}

// gate projection + pack: ahb[r] = [ bf16(h@gw1a+gb1) | bf16(h) ] (256B row),
// bbuf = h@gw1b.  k-major gw1 reads (coalesced, L1-hot).
__global__ __launch_bounds__(256) void gateproj_kernel(
    const float* __restrict__ h, const float* __restrict__ gw1,
    const float* __restrict__ gb1, ushort_t* __restrict__ ahb,
    float* __restrict__ bbuf, int N) {
    const int lane = threadIdx.x & 63;
    const int wid  = blockIdx.x * (blockDim.x >> 6) + (threadIdx.x >> 6);
    const int nw   = gridDim.x * (blockDim.x >> 6);
    const float gbl = gb1[lane];
    for (int r = wid; r < N; r += nw) {
        float hv = h[(size_t)r * 64 + lane];
        float aa = 0.f, bv = 0.f;
        #pragma unroll
        for (int k = 0; k < 64; ++k) {
            float tv = __shfl(hv, k, 64);
            aa = fmaf(gw1[(size_t)k * 64 + lane], tv, aa);
            bv = fmaf(gw1[(size_t)(64 + k) * 64 + lane], tv, bv);
        }
        ahb[(size_t)r * 128 + lane]      = f2bf(aa + gbl);
        ahb[(size_t)r * 128 + 64 + lane] = f2bf(hv);
        bbuf[(size_t)r * 64 + lane]      = bv;
    }
}

// fused gate + aggregation: wave-per-node, 16-lane group per edge, 2-way
// unroll (8 edges in flight/wave). Per edge: gather a+h from ONE 256B row,
// 4-step group reduce, sigmoid, fma into per-group float4 accumulators.
__global__ __launch_bounds__(256) void gateagg_kernel(
    const int* __restrict__ row_ptr, const int2* __restrict__ recs,
    const ushort_t* __restrict__ ahb, const float* __restrict__ bb,
    const float* __restrict__ gw2, const float* __restrict__ gb2,
    float* __restrict__ m, float* __restrict__ deg, int N) {
    const int lane = threadIdx.x & 63;
    const int sub  = lane & 15;
    const int grp  = lane >> 4;
    const float4 gv = ((const float4*)gw2)[sub];
    const float gb = gb2[0];
    const int wid  = blockIdx.x * (blockDim.x >> 6) + (threadIdx.x >> 6);
    const int nw   = gridDim.x * (blockDim.x >> 6);
    for (int n = wid; n < N; n += nw) {
        const int beg = row_ptr[n], end = row_ptr[n + 1];
        const float4 bv = *(const float4*)(bb + (size_t)n * 64 + sub * 4);
        float m0 = 0.f, m1 = 0.f, m2 = 0.f, m3 = 0.f, dacc = 0.f;
        int i = beg + grp;
        for (; i + 4 < end; i += 8) {              // two edges per iteration
            int2 rA = recs[i];
            int2 rB = recs[i + 4];
            const ushort_t* rowA = ahb + (size_t)rA.x * 128;
            const ushort_t* rowB = ahb + (size_t)rB.x * 128;
            ushort4 avA = *(const ushort4*)(rowA + sub * 4);
            ushort4 hvA = *(const ushort4*)(rowA + 64 + sub * 4);
            ushort4 avB = *(const ushort4*)(rowB + sub * 4);
            ushort4 hvB = *(const ushort4*)(rowB + 64 + sub * 4);
            float tA = fmaxf(bf2f(avA.x) + bv.x, 0.f) * gv.x
                     + fmaxf(bf2f(avA.y) + bv.y, 0.f) * gv.y
                     + fmaxf(bf2f(avA.z) + bv.z, 0.f) * gv.z
                     + fmaxf(bf2f(avA.w) + bv.w, 0.f) * gv.w;
            float tB = fmaxf(bf2f(avB.x) + bv.x, 0.f) * gv.x
                     + fmaxf(bf2f(avB.y) + bv.y, 0.f) * gv.y
                     + fmaxf(bf2f(avB.z) + bv.z, 0.f) * gv.z
                     + fmaxf(bf2f(avB.w) + bv.w, 0.f) * gv.w;
            #pragma unroll
            for (int o = 8; o > 0; o >>= 1) {
                tA += __shfl_xor(tA, o, 64);
                tB += __shfl_xor(tB, o, 64);
            }
            float wA = __int_as_float(rA.y) / (1.f + __expf(-(tA + gb)));
            float wB = __int_as_float(rB.y) / (1.f + __expf(-(tB + gb)));
            m0 = fmaf(wA, bf2f(hvA.x), m0); m0 = fmaf(wB, bf2f(hvB.x), m0);
            m1 = fmaf(wA, bf2f(hvA.y), m1); m1 = fmaf(wB, bf2f(hvB.y), m1);
            m2 = fmaf(wA, bf2f(hvA.z), m2); m2 = fmaf(wB, bf2f(hvB.z), m2);
            m3 = fmaf(wA, bf2f(hvA.w), m3); m3 = fmaf(wB, bf2f(hvB.w), m3);
            dacc += wA + wB;
        }
        if (i < end) {                             // tail edge for this group
            int2 r = recs[i];
            const ushort_t* row = ahb + (size_t)r.x * 128;
            ushort4 av = *(const ushort4*)(row + sub * 4);
            ushort4 hv = *(const ushort4*)(row + 64 + sub * 4);
            float t = fmaxf(bf2f(av.x) + bv.x, 0.f) * gv.x
                    + fmaxf(bf2f(av.y) + bv.y, 0.f) * gv.y
                    + fmaxf(bf2f(av.z) + bv.z, 0.f) * gv.z
                    + fmaxf(bf2f(av.w) + bv.w, 0.f) * gv.w;
            #pragma unroll
            for (int o = 8; o > 0; o >>= 1) t += __shfl_xor(t, o, 64);
            float w = __int_as_float(r.y) / (1.f + __expf(-(t + gb)));
            m0 = fmaf(w, bf2f(hv.x), m0);
            m1 = fmaf(w, bf2f(hv.y), m1);
            m2 = fmaf(w, bf2f(hv.z), m2);
            m3 = fmaf(w, bf2f(hv.w), m3);
            dacc += w;
        }
        // combine the 4 groups (xor 16, 32)
        #pragma unroll
        for (int o = 16; o < 64; o <<= 1) {
            m0 += __shfl_xor(m0, o, 64);
            m1 += __shfl_xor(m1, o, 64);
            m2 += __shfl_xor(m2, o, 64);
            m3 += __shfl_xor(m3, o, 64);
            dacc += __shfl_xor(dacc, o, 64);
        }
        if (lane < 16) {
            *(float4*)(m + (size_t)n * 64 + sub * 4) = make_float4(m0, m1, m2, m3);
            if (lane == 0) deg[n] = dacc;
        }
    }
}

// streaming update MLP + LayerNorm: neigh = m/deg; u = relu(neigh@W1+b1)@W2+b2;
// h_out = LN(h_in + u). k-major weights from global (L1-hot, coalesced).
__global__ __launch_bounds__(256) void upd_kernel(
    const float* __restrict__ m, const float* __restrict__ deg,
    const float* __restrict__ h_in,
    const float* __restrict__ w1, const float* __restrict__ b1,
    const float* __restrict__ w2, const float* __restrict__ b2,
    const float* __restrict__ lng, const float* __restrict__ lnb,
    float* __restrict__ h_out, int N) {
    const int lane = threadIdx.x & 63;
    const int wid  = blockIdx.x * (blockDim.x >> 6) + (threadIdx.x >> 6);
    const int nw   = gridDim.x * (blockDim.x >> 6);
    const float b1l = b1[lane], b2l = b2[lane];
    const float gl = lng[lane], bl = lnb[lane];
    for (int n = wid; n < N; n += nw) {
        float neigh = m[(size_t)n * 64 + lane] / (deg[n] + 1e-8f);
        float acc = 0.f;
        #pragma unroll
        for (int k = 0; k < 64; ++k) {
            float tv = __shfl(neigh, k, 64);
            acc = fmaf(w1[(size_t)k * 64 + lane], tv, acc);
        }
        float t = fmaxf(acc + b1l, 0.f);
        float acc2 = 0.f;
        #pragma unroll
        for (int k = 0; k < 64; ++k) {
            float tv = __shfl(t, k, 64);
            acc2 = fmaf(w2[(size_t)k * 64 + lane], tv, acc2);
        }
        float pre = h_in[(size_t)n * 64 + lane] + acc2 + b2l;
        float s1 = wave_sum64(pre);
        float s2 = wave_sum64(pre * pre);
        float mean = s1 * (1.0f / 64.0f);
        float var  = s2 * (1.0f / 64.0f) - mean * mean;
        float hn = (pre - mean) * rsqrtf(var + 1e-5f) * gl + bl;
        h_out[(size_t)n * 64 + lane] = hn;
    }
}

// U = softplus(h @ toU_w + toU_b), K=32
__global__ __launch_bounds__(256) void out_kernel(
    const float* __restrict__ h, const float* __restrict__ tw,
    const float* __restrict__ tb, float* __restrict__ U, int N) {
    int gid = blockIdx.x * blockDim.x + threadIdx.x;
    int n = gid >> 5;
    int k = gid & 31;
    if (n >= N) return;
    float acc = tb[k];
    const float* hr = h + (size_t)n * 64;
    #pragma unroll 8
    for (int j = 0; j < 64; ++j) acc = fmaf(hr[j], tw[j * 32 + k], acc);
    float sp = acc > 0.f ? acc + log1pf(__expf(-acc)) : log1pf(__expf(acc));
    U[(size_t)n * 32 + k] = sp;
}

extern "C" void kernel_launch(void* const* d_in, const int* in_sizes, int n_in,
                              void* d_out, int out_size, void* d_ws, size_t ws_size,
                              hipStream_t stream) {
    const float* x       = (const float*)d_in[0];
    const int*   src     = (const int*)d_in[1];
    const int*   dst     = (const int*)d_in[2];
    const float* base_w  = (const float*)d_in[3];
    const float* enc_w1  = (const float*)d_in[4];
    const float* enc_b1  = (const float*)d_in[5];
    const float* enc_w2  = (const float*)d_in[6];
    const float* enc_b2  = (const float*)d_in[7];
    const float* gate_w1 = (const float*)d_in[8];
    const float* gate_b1 = (const float*)d_in[9];
    const float* gate_w2 = (const float*)d_in[10];
    const float* gate_b2 = (const float*)d_in[11];
    const float* upd_w1  = (const float*)d_in[12];
    const float* upd_b1  = (const float*)d_in[13];
    const float* upd_w2  = (const float*)d_in[14];
    const float* upd_b2  = (const float*)d_in[15];
    const float* ln_g    = (const float*)d_in[16];
    const float* ln_b    = (const float*)d_in[17];
    const float* rho_raw = (const float*)d_in[18];
    const float* toU_w   = (const float*)d_in[19];
    const float* toU_b   = (const float*)d_in[20];

    const int N = in_sizes[18];          // 50000
    const int E = in_sizes[1];           // 800000
    const int L = 2;

    // workspace layout (float units), sections padded to 16B alignment
    float* ws  = (float*)d_ws;
    size_t off = 0;
    float* h0  = ws + off; off += (size_t)N * 64;
    float* h1  = ws + off; off += (size_t)N * 64;
    ushort_t* ahb = (ushort_t*)(ws + off); off += (size_t)N * 64;  // N*128 ushort
    float* bb  = ws + off; off += (size_t)N * 64;
    float* m   = ws + off; off += (size_t)N * 64;
    float* deg = ws + off; off += (size_t)((N + 3) & ~3);
    int* row_ptr = (int*)(ws + off); off += (size_t)((N + 1 + 3) & ~3);
    int* cnt     = (int*)(ws + off); off += (size_t)((N + 3) & ~3);
    int2* recs   = (int2*)(ws + off); off += (size_t)E * 2;   // (s,c)
    ushort_t* w1f = (ushort_t*)(ws + off); off += 8192;       // 16384 ushort
    ushort_t* w2f = (ushort_t*)(ws + off); off += 2048;       // 4096 ushort

    // pack enc weights into MFMA fragment order, then MFMA encoder
    pack_kernel<<<64, 256, 0, stream>>>(enc_w1, enc_w2, w1f, w2f);
    enc_kernel<<<(N + 63) / 64, 256, 0, stream>>>(x, w1f, enc_b1, w2f, enc_b2,
                                                  h0, N);

    // CSR build (dst-sorted edge records); rho folded into scatter
    hipMemsetAsync(cnt, 0, (size_t)N * sizeof(int), stream);
    hist_kernel<<<(E + 255) / 256, 256, 0, stream>>>(dst, cnt, E);
    scan_kernel<<<1, 1024, 0, stream>>>(cnt, row_ptr, N);
    hipMemsetAsync(cnt, 0, (size_t)N * sizeof(int), stream);
    scatter_kernel<<<(E + 255) / 256, 256, 0, stream>>>(src, dst, base_w, rho_raw,
                                                        row_ptr, cnt, recs, E);

    float* h_cur = h0;
    float* h_nxt = h1;
    for (int l = 0; l < L; ++l) {
        gateproj_kernel<<<1024, 256, 0, stream>>>(h_cur, gate_w1, gate_b1,
                                                  ahb, bb, N);
        gateagg_kernel<<<2048, 256, 0, stream>>>(row_ptr, recs, ahb, bb,
                                                 gate_w2, gate_b2, m, deg, N);
        upd_kernel<<<1024, 256, 0, stream>>>(
            m, deg, h_cur,
            upd_w1 + (size_t)l * 4096, upd_b1 + l * 64,
            upd_w2 + (size_t)l * 4096, upd_b2 + l * 64,
            ln_g + l * 64, ln_b + l * 64, h_nxt, N);
        float* tf = h_cur; h_cur = h_nxt; h_nxt = tf;
    }

    out_kernel<<<((N * 32) + 255) / 256, 256, 0, stream>>>(h_cur, toU_w, toU_b,
                                                           (float*)d_out, N);
}

// Round 14
// 337.240 us; speedup vs baseline: 2.0320x; 1.5808x over previous
//
#include <hip/hip_runtime.h>
#include <math.h>

// ---------------------------------------------------------------------------
// StageA GNN: pack -> MFMA-enc -> CSR -> L x (MFMA-gateproj, gateagg, MFMA-upd)
// -> head.  R14: gateproj and upd ported to mfma_f32_16x16x32_bf16 using the
// R13-verified fragment layouts. upd fuses residual+LayerNorm in D-layout
// (row = 16-lane group: 4-step shfl_xor reduce). gateagg = proven R12.
// ---------------------------------------------------------------------------

typedef unsigned short ushort_t;
typedef __attribute__((ext_vector_type(8))) short bf16x8;
typedef __attribute__((ext_vector_type(4))) float f32x4;

__device__ __forceinline__ float bf2f(ushort_t u) {
    return __uint_as_float(((unsigned int)u) << 16);
}
__device__ __forceinline__ ushort_t f2bf(float f) {
    unsigned int x = __float_as_uint(f);
    unsigned int lsb = (x >> 16) & 1u;
    x += 0x7fffu + lsb;                 // round-to-nearest-even
    return (ushort_t)(x >> 16);
}

// pack all GEMV/GEMM weights into MFMA B-fragment order (bf16).
// fragment: elem i of lane l = B[k = kb*32 + (l>>4)*8 + i][n = nt*16 + (l&15)]
__global__ __launch_bounds__(256) void pack_kernel(
    const float* __restrict__ w1, const float* __restrict__ w2,
    const float* __restrict__ gw1, const float* __restrict__ uw1,
    const float* __restrict__ uw2,
    ushort_t* __restrict__ w1f, ushort_t* __restrict__ w2f,
    ushort_t* __restrict__ g1f, ushort_t* __restrict__ u1f,
    ushort_t* __restrict__ u2f) {
    int t = blockIdx.x * 256 + threadIdx.x;
    if (t < 16384) {   // w1f: nt(4) kb(8) lane(64) i(8)
        int i = t & 7, l = (t >> 3) & 63, kb = (t >> 9) & 7, nt = t >> 12;
        int k = kb * 32 + (l >> 4) * 8 + i, n = nt * 16 + (l & 15);
        w1f[t] = f2bf(w1[(size_t)k * 64 + n]);
    }
    if (t < 4096) {    // w2f: nt(4) kb(2)
        int i = t & 7, l = (t >> 3) & 63, kb = (t >> 9) & 1, nt = t >> 10;
        int k = kb * 32 + (l >> 4) * 8 + i, n = nt * 16 + (l & 15);
        w2f[t] = f2bf(w2[(size_t)k * 64 + n]);
    }
    if (t < 8192) {    // g1f: j(8)=part*4+nt, kb(2); gw1 is [128][64]
        int i = t & 7, l = (t >> 3) & 63, kb = (t >> 9) & 1, j = t >> 10;
        int part = j >> 2, nt = j & 3;
        int k = part * 64 + kb * 32 + (l >> 4) * 8 + i, n = nt * 16 + (l & 15);
        g1f[t] = f2bf(gw1[(size_t)k * 64 + n]);
    }
    if (t < 8192) {    // u1f/u2f: layer(2) nt(4) kb(2)
        int i = t & 7, l = (t >> 3) & 63, kb = (t >> 9) & 1;
        int nt = (t >> 10) & 3, lay = t >> 12;
        int k = kb * 32 + (l >> 4) * 8 + i, n = nt * 16 + (l & 15);
        u1f[t] = f2bf(uw1[(size_t)lay * 4096 + (size_t)k * 64 + n]);
        u2f[t] = f2bf(uw2[(size_t)lay * 4096 + (size_t)k * 64 + n]);
    }
}

// MFMA encoder: h = relu(relu(x@W1+b1)@W2+b2), block = 64 rows, wave = 16.
__global__ __launch_bounds__(256) void enc_kernel(
    const float* __restrict__ x, const ushort_t* __restrict__ w1f,
    const float* __restrict__ b1, const ushort_t* __restrict__ w2f,
    const float* __restrict__ b2, float* __restrict__ h, int N) {
    __shared__ ushort_t xls[4][16][264];
    __shared__ ushort_t tls[4][16][72];
    const int tid  = threadIdx.x;
    const int lane = tid & 63;
    const int w    = tid >> 6;
    const int m    = lane & 15;
    const int g    = lane >> 4;
    const int rbase = blockIdx.x * 64;
    for (int p = tid; p < 64 * 128; p += 256) {
        int row = p >> 7, kp = p & 127;
        int grow = rbase + row;
        float2 v = (grow < N) ? *(const float2*)(x + (size_t)grow * 256 + kp * 2)
                              : make_float2(0.f, 0.f);
        unsigned int pk = (unsigned int)f2bf(v.x) | ((unsigned int)f2bf(v.y) << 16);
        *(unsigned int*)&xls[row >> 4][row & 15][kp * 2] = pk;
    }
    __syncthreads();
    f32x4 acc[4] = {{0,0,0,0},{0,0,0,0},{0,0,0,0},{0,0,0,0}};
    #pragma unroll
    for (int kb = 0; kb < 8; ++kb) {
        bf16x8 a = *(const bf16x8*)&xls[w][m][kb * 32 + g * 8];
        #pragma unroll
        for (int nt = 0; nt < 4; ++nt) {
            bf16x8 b = *(const bf16x8*)(w1f + (((size_t)nt * 8 + kb) * 64 + lane) * 8);
            acc[nt] = __builtin_amdgcn_mfma_f32_16x16x32_bf16(a, b, acc[nt], 0, 0, 0);
        }
    }
    #pragma unroll
    for (int nt = 0; nt < 4; ++nt) {
        float bb1 = b1[nt * 16 + m];
        #pragma unroll
        for (int r = 0; r < 4; ++r) {
            float tv = fmaxf(acc[nt][r] + bb1, 0.f);
            tls[w][g * 4 + r][nt * 16 + m] = f2bf(tv);
        }
    }
    f32x4 acc2[4] = {{0,0,0,0},{0,0,0,0},{0,0,0,0},{0,0,0,0}};
    #pragma unroll
    for (int kb = 0; kb < 2; ++kb) {
        bf16x8 a2 = *(const bf16x8*)&tls[w][m][kb * 32 + g * 8];
        #pragma unroll
        for (int nt = 0; nt < 4; ++nt) {
            bf16x8 b = *(const bf16x8*)(w2f + (((size_t)nt * 2 + kb) * 64 + lane) * 8);
            acc2[nt] = __builtin_amdgcn_mfma_f32_16x16x32_bf16(a2, b, acc2[nt], 0, 0, 0);
        }
    }
    #pragma unroll
    for (int nt = 0; nt < 4; ++nt) {
        float bb2 = b2[nt * 16 + m];
        #pragma unroll
        for (int r = 0; r < 4; ++r) {
            int grow = rbase + w * 16 + g * 4 + r;
            if (grow < N)
                h[(size_t)grow * 64 + nt * 16 + m] = fmaxf(acc2[nt][r] + bb2, 0.f);
        }
    }
}

// ---- CSR build ----
__global__ __launch_bounds__(256) void hist_kernel(
    const int* __restrict__ dst, int* __restrict__ cnt, int E) {
    for (int e = blockIdx.x * blockDim.x + threadIdx.x; e < E;
         e += gridDim.x * blockDim.x)
        atomicAdd(&cnt[dst[e]], 1);
}

__global__ __launch_bounds__(1024) void scan_kernel(
    const int* __restrict__ cnt, int* __restrict__ row_ptr, int N) {
    __shared__ int sums[1024];
    const int tid = threadIdx.x;
    const int chunk = (N + 1023) / 1024;
    const int beg = tid * chunk;
    const int end = min(beg + chunk, N);
    int s = 0;
    for (int i = beg; i < end; ++i) s += cnt[i];
    sums[tid] = s;
    __syncthreads();
    for (int off = 1; off < 1024; off <<= 1) {
        int v = (tid >= off) ? sums[tid - off] : 0;
        __syncthreads();
        sums[tid] += v;
        __syncthreads();
    }
    int run = (tid == 0) ? 0 : sums[tid - 1];
    for (int i = beg; i < end; ++i) {
        row_ptr[i] = run;
        run += cnt[i];
    }
    if (tid == 1023) row_ptr[N] = sums[1023];
}

__global__ __launch_bounds__(256) void scatter_kernel(
    const int* __restrict__ src, const int* __restrict__ dst,
    const float* __restrict__ base_w, const float* __restrict__ rr,
    const int* __restrict__ row_ptr, int* __restrict__ fill,
    int2* __restrict__ recs, int E) {
    for (int e = blockIdx.x * blockDim.x + threadIdx.x; e < E;
         e += gridDim.x * blockDim.x) {
        int s = src[e], d = dst[e];
        int pos = row_ptr[d] + atomicAdd(&fill[d], 1);
        float rs = 1.f / (1.f + __expf(-rr[s]));
        float rd = 1.f / (1.f + __expf(-rr[d]));
        float c = base_w[e] * rs * rd;
        recs[pos] = make_int2(s, __float_as_int(c));
    }
}

// MFMA gate projection: [a | b] = h @ gw1 (64x128); ahb = [bf16 a | bf16 h],
// bbuf = fp32 b. Block = 64 rows, wave = 16.
__global__ __launch_bounds__(256) void gateproj_kernel(
    const float* __restrict__ h, const ushort_t* __restrict__ g1f,
    const float* __restrict__ gb1, ushort_t* __restrict__ ahb,
    float* __restrict__ bbuf, int N) {
    __shared__ ushort_t hls[4][16][72];
    const int tid  = threadIdx.x;
    const int lane = tid & 63;
    const int w    = tid >> 6;
    const int m_   = lane & 15;
    const int g    = lane >> 4;
    const int rbase = blockIdx.x * 64;
    for (int p = tid; p < 64 * 32; p += 256) {
        int row = p >> 5, c2 = p & 31;
        int grow = rbase + row;
        float2 v = (grow < N) ? *(const float2*)(h + (size_t)grow * 64 + c2 * 2)
                              : make_float2(0.f, 0.f);
        unsigned int pk = (unsigned int)f2bf(v.x) | ((unsigned int)f2bf(v.y) << 16);
        *(unsigned int*)&hls[row >> 4][row & 15][c2 * 2] = pk;
    }
    __syncthreads();
    f32x4 acc[8] = {{0,0,0,0},{0,0,0,0},{0,0,0,0},{0,0,0,0},
                    {0,0,0,0},{0,0,0,0},{0,0,0,0},{0,0,0,0}};
    #pragma unroll
    for (int kb = 0; kb < 2; ++kb) {
        bf16x8 a = *(const bf16x8*)&hls[w][m_][kb * 32 + g * 8];
        #pragma unroll
        for (int j = 0; j < 8; ++j) {
            bf16x8 b = *(const bf16x8*)(g1f + (((size_t)j * 2 + kb) * 64 + lane) * 8);
            acc[j] = __builtin_amdgcn_mfma_f32_16x16x32_bf16(a, b, acc[j], 0, 0, 0);
        }
    }
    #pragma unroll
    for (int nt = 0; nt < 4; ++nt) {
        float gbl = gb1[nt * 16 + m_];
        #pragma unroll
        for (int r = 0; r < 4; ++r) {
            int grow = rbase + w * 16 + g * 4 + r;
            if (grow < N) {
                ahb[(size_t)grow * 128 + nt * 16 + m_] = f2bf(acc[nt][r] + gbl);
                bbuf[(size_t)grow * 64 + nt * 16 + m_] = acc[nt + 4][r];
            }
        }
    }
    // copy bf16 h half into ahb rows (coalesced 8B/thread from LDS)
    for (int p = tid; p < 64 * 16; p += 256) {
        int row = p >> 4, c4 = p & 15;
        int grow = rbase + row;
        if (grow < N)
            *(ushort4*)(ahb + (size_t)grow * 128 + 64 + c4 * 4) =
                *(const ushort4*)&hls[row >> 4][row & 15][c4 * 4];
    }
}

// fused gate + aggregation (R12, proven): wave-per-node, 16-lane group/edge.
__global__ __launch_bounds__(256) void gateagg_kernel(
    const int* __restrict__ row_ptr, const int2* __restrict__ recs,
    const ushort_t* __restrict__ ahb, const float* __restrict__ bb,
    const float* __restrict__ gw2, const float* __restrict__ gb2,
    float* __restrict__ m, float* __restrict__ deg, int N) {
    const int lane = threadIdx.x & 63;
    const int sub  = lane & 15;
    const int grp  = lane >> 4;
    const float4 gv = ((const float4*)gw2)[sub];
    const float gb = gb2[0];
    const int wid  = blockIdx.x * (blockDim.x >> 6) + (threadIdx.x >> 6);
    const int nw   = gridDim.x * (blockDim.x >> 6);
    for (int n = wid; n < N; n += nw) {
        const int beg = row_ptr[n], end = row_ptr[n + 1];
        const float4 bv = *(const float4*)(bb + (size_t)n * 64 + sub * 4);
        float m0 = 0.f, m1 = 0.f, m2 = 0.f, m3 = 0.f, dacc = 0.f;
        int i = beg + grp;
        for (; i + 4 < end; i += 8) {
            int2 rA = recs[i];
            int2 rB = recs[i + 4];
            const ushort_t* rowA = ahb + (size_t)rA.x * 128;
            const ushort_t* rowB = ahb + (size_t)rB.x * 128;
            ushort4 avA = *(const ushort4*)(rowA + sub * 4);
            ushort4 hvA = *(const ushort4*)(rowA + 64 + sub * 4);
            ushort4 avB = *(const ushort4*)(rowB + sub * 4);
            ushort4 hvB = *(const ushort4*)(rowB + 64 + sub * 4);
            float tA = fmaxf(bf2f(avA.x) + bv.x, 0.f) * gv.x
                     + fmaxf(bf2f(avA.y) + bv.y, 0.f) * gv.y
                     + fmaxf(bf2f(avA.z) + bv.z, 0.f) * gv.z
                     + fmaxf(bf2f(avA.w) + bv.w, 0.f) * gv.w;
            float tB = fmaxf(bf2f(avB.x) + bv.x, 0.f) * gv.x
                     + fmaxf(bf2f(avB.y) + bv.y, 0.f) * gv.y
                     + fmaxf(bf2f(avB.z) + bv.z, 0.f) * gv.z
                     + fmaxf(bf2f(avB.w) + bv.w, 0.f) * gv.w;
            #pragma unroll
            for (int o = 8; o > 0; o >>= 1) {
                tA += __shfl_xor(tA, o, 64);
                tB += __shfl_xor(tB, o, 64);
            }
            float wA = __int_as_float(rA.y) / (1.f + __expf(-(tA + gb)));
            float wB = __int_as_float(rB.y) / (1.f + __expf(-(tB + gb)));
            m0 = fmaf(wA, bf2f(hvA.x), m0); m0 = fmaf(wB, bf2f(hvB.x), m0);
            m1 = fmaf(wA, bf2f(hvA.y), m1); m1 = fmaf(wB, bf2f(hvB.y), m1);
            m2 = fmaf(wA, bf2f(hvA.z), m2); m2 = fmaf(wB, bf2f(hvB.z), m2);
            m3 = fmaf(wA, bf2f(hvA.w), m3); m3 = fmaf(wB, bf2f(hvB.w), m3);
            dacc += wA + wB;
        }
        if (i < end) {
            int2 r = recs[i];
            const ushort_t* row = ahb + (size_t)r.x * 128;
            ushort4 av = *(const ushort4*)(row + sub * 4);
            ushort4 hv = *(const ushort4*)(row + 64 + sub * 4);
            float t = fmaxf(bf2f(av.x) + bv.x, 0.f) * gv.x
                    + fmaxf(bf2f(av.y) + bv.y, 0.f) * gv.y
                    + fmaxf(bf2f(av.z) + bv.z, 0.f) * gv.z
                    + fmaxf(bf2f(av.w) + bv.w, 0.f) * gv.w;
            #pragma unroll
            for (int o = 8; o > 0; o >>= 1) t += __shfl_xor(t, o, 64);
            float w = __int_as_float(r.y) / (1.f + __expf(-(t + gb)));
            m0 = fmaf(w, bf2f(hv.x), m0);
            m1 = fmaf(w, bf2f(hv.y), m1);
            m2 = fmaf(w, bf2f(hv.z), m2);
            m3 = fmaf(w, bf2f(hv.w), m3);
            dacc += w;
        }
        #pragma unroll
        for (int o = 16; o < 64; o <<= 1) {
            m0 += __shfl_xor(m0, o, 64);
            m1 += __shfl_xor(m1, o, 64);
            m2 += __shfl_xor(m2, o, 64);
            m3 += __shfl_xor(m3, o, 64);
            dacc += __shfl_xor(dacc, o, 64);
        }
        if (lane < 16) {
            *(float4*)(m + (size_t)n * 64 + sub * 4) = make_float4(m0, m1, m2, m3);
            if (lane == 0) deg[n] = dacc;
        }
    }
}

// MFMA update + residual + LayerNorm. Block = 64 rows, wave = 16.
// LN in D-layout: per (g,r) the row's 64 features = 16 lanes x 4 nt regs;
// reduce with 4-step shfl_xor(1,2,4,8) within the 16-lane group.
__global__ __launch_bounds__(256) void upd_kernel(
    const float* __restrict__ m, const float* __restrict__ deg,
    const float* __restrict__ h_in,
    const ushort_t* __restrict__ u1f, const float* __restrict__ b1,
    const ushort_t* __restrict__ u2f, const float* __restrict__ b2,
    const float* __restrict__ lng, const float* __restrict__ lnb,
    float* __restrict__ h_out, int N) {
    __shared__ ushort_t mls[4][16][72];
    __shared__ ushort_t tls[4][16][72];
    const int tid  = threadIdx.x;
    const int lane = tid & 63;
    const int w    = tid >> 6;
    const int m_   = lane & 15;
    const int g    = lane >> 4;
    const int rbase = blockIdx.x * 64;
    for (int p = tid; p < 64 * 32; p += 256) {
        int row = p >> 5, c2 = p & 31;
        int grow = rbase + row;
        float2 v = make_float2(0.f, 0.f);
        if (grow < N) {
            float dg = deg[grow] + 1e-8f;
            float2 mv = *(const float2*)(m + (size_t)grow * 64 + c2 * 2);
            v = make_float2(mv.x / dg, mv.y / dg);
        }
        unsigned int pk = (unsigned int)f2bf(v.x) | ((unsigned int)f2bf(v.y) << 16);
        *(unsigned int*)&mls[row >> 4][row & 15][c2 * 2] = pk;
    }
    __syncthreads();
    f32x4 acc[4] = {{0,0,0,0},{0,0,0,0},{0,0,0,0},{0,0,0,0}};
    #pragma unroll
    for (int kb = 0; kb < 2; ++kb) {
        bf16x8 a = *(const bf16x8*)&mls[w][m_][kb * 32 + g * 8];
        #pragma unroll
        for (int nt = 0; nt < 4; ++nt) {
            bf16x8 b = *(const bf16x8*)(u1f + (((size_t)nt * 2 + kb) * 64 + lane) * 8);
            acc[nt] = __builtin_amdgcn_mfma_f32_16x16x32_bf16(a, b, acc[nt], 0, 0, 0);
        }
    }
    #pragma unroll
    for (int nt = 0; nt < 4; ++nt) {
        float bb1 = b1[nt * 16 + m_];
        #pragma unroll
        for (int r = 0; r < 4; ++r)
            tls[w][g * 4 + r][nt * 16 + m_] = f2bf(fmaxf(acc[nt][r] + bb1, 0.f));
    }
    f32x4 acc2[4] = {{0,0,0,0},{0,0,0,0},{0,0,0,0},{0,0,0,0}};
    #pragma unroll
    for (int kb = 0; kb < 2; ++kb) {
        bf16x8 a2 = *(const bf16x8*)&tls[w][m_][kb * 32 + g * 8];
        #pragma unroll
        for (int nt = 0; nt < 4; ++nt) {
            bf16x8 b = *(const bf16x8*)(u2f + (((size_t)nt * 2 + kb) * 64 + lane) * 8);
            acc2[nt] = __builtin_amdgcn_mfma_f32_16x16x32_bf16(a2, b, acc2[nt], 0, 0, 0);
        }
    }
    #pragma unroll
    for (int r = 0; r < 4; ++r) {
        const int grow = rbase + w * 16 + g * 4 + r;
        float pre[4];
        float s1 = 0.f, s2 = 0.f;
        #pragma unroll
        for (int nt = 0; nt < 4; ++nt) {
            float hv = (grow < N) ? h_in[(size_t)grow * 64 + nt * 16 + m_] : 0.f;
            pre[nt] = acc2[nt][r] + b2[nt * 16 + m_] + hv;
            s1 += pre[nt];
            s2 += pre[nt] * pre[nt];
        }
        #pragma unroll
        for (int o = 1; o < 16; o <<= 1) {
            s1 += __shfl_xor(s1, o, 64);
            s2 += __shfl_xor(s2, o, 64);
        }
        float mean = s1 * (1.0f / 64.0f);
        float var  = s2 * (1.0f / 64.0f) - mean * mean;
        float rinv = rsqrtf(var + 1e-5f);
        if (grow < N) {
            #pragma unroll
            for (int nt = 0; nt < 4; ++nt)
                h_out[(size_t)grow * 64 + nt * 16 + m_] =
                    (pre[nt] - mean) * rinv * lng[nt * 16 + m_] + lnb[nt * 16 + m_];
        }
    }
}

// U = softplus(h @ toU_w + toU_b), K=32
__global__ __launch_bounds__(256) void out_kernel(
    const float* __restrict__ h, const float* __restrict__ tw,
    const float* __restrict__ tb, float* __restrict__ U, int N) {
    int gid = blockIdx.x * blockDim.x + threadIdx.x;
    int n = gid >> 5;
    int k = gid & 31;
    if (n >= N) return;
    float acc = tb[k];
    const float* hr = h + (size_t)n * 64;
    #pragma unroll 8
    for (int j = 0; j < 64; ++j) acc = fmaf(hr[j], tw[j * 32 + k], acc);
    float sp = acc > 0.f ? acc + log1pf(__expf(-acc)) : log1pf(__expf(acc));
    U[(size_t)n * 32 + k] = sp;
}

extern "C" void kernel_launch(void* const* d_in, const int* in_sizes, int n_in,
                              void* d_out, int out_size, void* d_ws, size_t ws_size,
                              hipStream_t stream) {
    const float* x       = (const float*)d_in[0];
    const int*   src     = (const int*)d_in[1];
    const int*   dst     = (const int*)d_in[2];
    const float* base_w  = (const float*)d_in[3];
    const float* enc_w1  = (const float*)d_in[4];
    const float* enc_b1  = (const float*)d_in[5];
    const float* enc_w2  = (const float*)d_in[6];
    const float* enc_b2  = (const float*)d_in[7];
    const float* gate_w1 = (const float*)d_in[8];
    const float* gate_b1 = (const float*)d_in[9];
    const float* gate_w2 = (const float*)d_in[10];
    const float* gate_b2 = (const float*)d_in[11];
    const float* upd_w1  = (const float*)d_in[12];
    const float* upd_b1  = (const float*)d_in[13];
    const float* upd_w2  = (const float*)d_in[14];
    const float* upd_b2  = (const float*)d_in[15];
    const float* ln_g    = (const float*)d_in[16];
    const float* ln_b    = (const float*)d_in[17];
    const float* rho_raw = (const float*)d_in[18];
    const float* toU_w   = (const float*)d_in[19];
    const float* toU_b   = (const float*)d_in[20];

    const int N = in_sizes[18];          // 50000
    const int E = in_sizes[1];           // 800000
    const int L = 2;

    // workspace layout (float units)
    float* ws  = (float*)d_ws;
    size_t off = 0;
    float* h0  = ws + off; off += (size_t)N * 64;
    float* h1  = ws + off; off += (size_t)N * 64;
    ushort_t* ahb = (ushort_t*)(ws + off); off += (size_t)N * 64;  // N*128 ushort
    float* bb  = ws + off; off += (size_t)N * 64;
    float* m   = ws + off; off += (size_t)N * 64;
    float* deg = ws + off; off += (size_t)((N + 3) & ~3);
    int* row_ptr = (int*)(ws + off); off += (size_t)((N + 1 + 3) & ~3);
    int* cnt     = (int*)(ws + off); off += (size_t)((N + 3) & ~3);
    int2* recs   = (int2*)(ws + off); off += (size_t)E * 2;   // (s,c)
    ushort_t* w1f = (ushort_t*)(ws + off); off += 8192;       // 16384 ushort
    ushort_t* w2f = (ushort_t*)(ws + off); off += 2048;       // 4096 ushort
    ushort_t* g1f = (ushort_t*)(ws + off); off += 4096;       // 8192 ushort
    ushort_t* u1f = (ushort_t*)(ws + off); off += 4096;       // 8192 ushort
    ushort_t* u2f = (ushort_t*)(ws + off); off += 4096;       // 8192 ushort

    pack_kernel<<<64, 256, 0, stream>>>(enc_w1, enc_w2, gate_w1, upd_w1, upd_w2,
                                        w1f, w2f, g1f, u1f, u2f);
    enc_kernel<<<(N + 63) / 64, 256, 0, stream>>>(x, w1f, enc_b1, w2f, enc_b2,
                                                  h0, N);

    // CSR build; rho folded into scatter
    hipMemsetAsync(cnt, 0, (size_t)N * sizeof(int), stream);
    hist_kernel<<<(E + 255) / 256, 256, 0, stream>>>(dst, cnt, E);
    scan_kernel<<<1, 1024, 0, stream>>>(cnt, row_ptr, N);
    hipMemsetAsync(cnt, 0, (size_t)N * sizeof(int), stream);
    scatter_kernel<<<(E + 255) / 256, 256, 0, stream>>>(src, dst, base_w, rho_raw,
                                                        row_ptr, cnt, recs, E);

    const int nblk64 = (N + 63) / 64;
    float* h_cur = h0;
    float* h_nxt = h1;
    for (int l = 0; l < L; ++l) {
        gateproj_kernel<<<nblk64, 256, 0, stream>>>(h_cur, g1f, gate_b1,
                                                    ahb, bb, N);
        gateagg_kernel<<<2048, 256, 0, stream>>>(row_ptr, recs, ahb, bb,
                                                 gate_w2, gate_b2, m, deg, N);
        upd_kernel<<<nblk64, 256, 0, stream>>>(
            m, deg, h_cur,
            u1f + (size_t)l * 4096, upd_b1 + l * 64,
            u2f + (size_t)l * 4096, upd_b2 + l * 64,
            ln_g + l * 64, ln_b + l * 64, h_nxt, N);
        float* tf = h_cur; h_cur = h_nxt; h_nxt = tf;
    }

    out_kernel<<<((N * 32) + 255) / 256, 256, 0, stream>>>(h_cur, toU_w, toU_b,
                                                           (float*)d_out, N);
}

// Round 15
// 270.366 us; speedup vs baseline: 2.5346x; 1.2473x over previous
//
#include <hip/hip_runtime.h>
#include <math.h>

// ---------------------------------------------------------------------------
// StageA GNN: pack -> MFMA-enc -> CSR(parallel scan) -> L x (MFMA-gateproj,
// gateagg, MFMA-upd) -> head.
// R15: replace the single-block scan (78us, 0.15% occupancy -- the largest
// dispatch after R14's MFMA ports) with a 3-phase hierarchical scan (~10us).
// All compute kernels unchanged from proven R14.
// ---------------------------------------------------------------------------

typedef unsigned short ushort_t;
typedef __attribute__((ext_vector_type(8))) short bf16x8;
typedef __attribute__((ext_vector_type(4))) float f32x4;

__device__ __forceinline__ float bf2f(ushort_t u) {
    return __uint_as_float(((unsigned int)u) << 16);
}
__device__ __forceinline__ ushort_t f2bf(float f) {
    unsigned int x = __float_as_uint(f);
    unsigned int lsb = (x >> 16) & 1u;
    x += 0x7fffu + lsb;                 // round-to-nearest-even
    return (ushort_t)(x >> 16);
}

// pack all GEMV/GEMM weights into MFMA B-fragment order (bf16).
__global__ __launch_bounds__(256) void pack_kernel(
    const float* __restrict__ w1, const float* __restrict__ w2,
    const float* __restrict__ gw1, const float* __restrict__ uw1,
    const float* __restrict__ uw2,
    ushort_t* __restrict__ w1f, ushort_t* __restrict__ w2f,
    ushort_t* __restrict__ g1f, ushort_t* __restrict__ u1f,
    ushort_t* __restrict__ u2f) {
    int t = blockIdx.x * 256 + threadIdx.x;
    if (t < 16384) {   // w1f: nt(4) kb(8) lane(64) i(8)
        int i = t & 7, l = (t >> 3) & 63, kb = (t >> 9) & 7, nt = t >> 12;
        int k = kb * 32 + (l >> 4) * 8 + i, n = nt * 16 + (l & 15);
        w1f[t] = f2bf(w1[(size_t)k * 64 + n]);
    }
    if (t < 4096) {    // w2f: nt(4) kb(2)
        int i = t & 7, l = (t >> 3) & 63, kb = (t >> 9) & 1, nt = t >> 10;
        int k = kb * 32 + (l >> 4) * 8 + i, n = nt * 16 + (l & 15);
        w2f[t] = f2bf(w2[(size_t)k * 64 + n]);
    }
    if (t < 8192) {    // g1f: j(8)=part*4+nt, kb(2); gw1 is [128][64]
        int i = t & 7, l = (t >> 3) & 63, kb = (t >> 9) & 1, j = t >> 10;
        int part = j >> 2, nt = j & 3;
        int k = part * 64 + kb * 32 + (l >> 4) * 8 + i, n = nt * 16 + (l & 15);
        g1f[t] = f2bf(gw1[(size_t)k * 64 + n]);
    }
    if (t < 8192) {    // u1f/u2f: layer(2) nt(4) kb(2)
        int i = t & 7, l = (t >> 3) & 63, kb = (t >> 9) & 1;
        int nt = (t >> 10) & 3, lay = t >> 12;
        int k = kb * 32 + (l >> 4) * 8 + i, n = nt * 16 + (l & 15);
        u1f[t] = f2bf(uw1[(size_t)lay * 4096 + (size_t)k * 64 + n]);
        u2f[t] = f2bf(uw2[(size_t)lay * 4096 + (size_t)k * 64 + n]);
    }
}

// MFMA encoder: h = relu(relu(x@W1+b1)@W2+b2), block = 64 rows, wave = 16.
__global__ __launch_bounds__(256) void enc_kernel(
    const float* __restrict__ x, const ushort_t* __restrict__ w1f,
    const float* __restrict__ b1, const ushort_t* __restrict__ w2f,
    const float* __restrict__ b2, float* __restrict__ h, int N) {
    __shared__ ushort_t xls[4][16][264];
    __shared__ ushort_t tls[4][16][72];
    const int tid  = threadIdx.x;
    const int lane = tid & 63;
    const int w    = tid >> 6;
    const int m    = lane & 15;
    const int g    = lane >> 4;
    const int rbase = blockIdx.x * 64;
    for (int p = tid; p < 64 * 128; p += 256) {
        int row = p >> 7, kp = p & 127;
        int grow = rbase + row;
        float2 v = (grow < N) ? *(const float2*)(x + (size_t)grow * 256 + kp * 2)
                              : make_float2(0.f, 0.f);
        unsigned int pk = (unsigned int)f2bf(v.x) | ((unsigned int)f2bf(v.y) << 16);
        *(unsigned int*)&xls[row >> 4][row & 15][kp * 2] = pk;
    }
    __syncthreads();
    f32x4 acc[4] = {{0,0,0,0},{0,0,0,0},{0,0,0,0},{0,0,0,0}};
    #pragma unroll
    for (int kb = 0; kb < 8; ++kb) {
        bf16x8 a = *(const bf16x8*)&xls[w][m][kb * 32 + g * 8];
        #pragma unroll
        for (int nt = 0; nt < 4; ++nt) {
            bf16x8 b = *(const bf16x8*)(w1f + (((size_t)nt * 8 + kb) * 64 + lane) * 8);
            acc[nt] = __builtin_amdgcn_mfma_f32_16x16x32_bf16(a, b, acc[nt], 0, 0, 0);
        }
    }
    #pragma unroll
    for (int nt = 0; nt < 4; ++nt) {
        float bb1 = b1[nt * 16 + m];
        #pragma unroll
        for (int r = 0; r < 4; ++r) {
            float tv = fmaxf(acc[nt][r] + bb1, 0.f);
            tls[w][g * 4 + r][nt * 16 + m] = f2bf(tv);
        }
    }
    f32x4 acc2[4] = {{0,0,0,0},{0,0,0,0},{0,0,0,0},{0,0,0,0}};
    #pragma unroll
    for (int kb = 0; kb < 2; ++kb) {
        bf16x8 a2 = *(const bf16x8*)&tls[w][m][kb * 32 + g * 8];
        #pragma unroll
        for (int nt = 0; nt < 4; ++nt) {
            bf16x8 b = *(const bf16x8*)(w2f + (((size_t)nt * 2 + kb) * 64 + lane) * 8);
            acc2[nt] = __builtin_amdgcn_mfma_f32_16x16x32_bf16(a2, b, acc2[nt], 0, 0, 0);
        }
    }
    #pragma unroll
    for (int nt = 0; nt < 4; ++nt) {
        float bb2 = b2[nt * 16 + m];
        #pragma unroll
        for (int r = 0; r < 4; ++r) {
            int grow = rbase + w * 16 + g * 4 + r;
            if (grow < N)
                h[(size_t)grow * 64 + nt * 16 + m] = fmaxf(acc2[nt][r] + bb2, 0.f);
        }
    }
}

// ---- CSR build ----
__global__ __launch_bounds__(256) void hist_kernel(
    const int* __restrict__ dst, int* __restrict__ cnt, int E) {
    for (int e = blockIdx.x * blockDim.x + threadIdx.x; e < E;
         e += gridDim.x * blockDim.x)
        atomicAdd(&cnt[dst[e]], 1);
}

// 3-phase hierarchical exclusive scan of cnt[N] -> row_ptr[N+1]
__global__ __launch_bounds__(256) void scan1_kernel(
    const int* __restrict__ cnt, int* __restrict__ bsum, int N) {
    __shared__ int red[256];
    int i = blockIdx.x * 256 + threadIdx.x;
    red[threadIdx.x] = (i < N) ? cnt[i] : 0;
    __syncthreads();
    for (int off = 128; off > 0; off >>= 1) {
        if (threadIdx.x < off) red[threadIdx.x] += red[threadIdx.x + off];
        __syncthreads();
    }
    if (threadIdx.x == 0) bsum[blockIdx.x] = red[0];
}

__global__ __launch_bounds__(1024) void scan2_kernel(
    int* __restrict__ bsum, int nb) {
    __shared__ int s[1024];
    int v = (threadIdx.x < nb) ? bsum[threadIdx.x] : 0;
    s[threadIdx.x] = v;
    __syncthreads();
    for (int off = 1; off < 1024; off <<= 1) {
        int t = (threadIdx.x >= off) ? s[threadIdx.x - off] : 0;
        __syncthreads();
        s[threadIdx.x] += t;
        __syncthreads();
    }
    if (threadIdx.x < nb) bsum[threadIdx.x] = s[threadIdx.x] - v;  // exclusive
}

__global__ __launch_bounds__(256) void scan3_kernel(
    const int* __restrict__ cnt, const int* __restrict__ bsum,
    int* __restrict__ row_ptr, int N) {
    __shared__ int s[256];
    int i = blockIdx.x * 256 + threadIdx.x;
    int v = (i < N) ? cnt[i] : 0;
    s[threadIdx.x] = v;
    __syncthreads();
    for (int off = 1; off < 256; off <<= 1) {
        int t = (threadIdx.x >= off) ? s[threadIdx.x - off] : 0;
        __syncthreads();
        s[threadIdx.x] += t;
        __syncthreads();
    }
    if (i < N) row_ptr[i] = bsum[blockIdx.x] + s[threadIdx.x] - v;  // exclusive
    if (i == N - 1) row_ptr[N] = bsum[blockIdx.x] + s[threadIdx.x]; // total
}

__global__ __launch_bounds__(256) void scatter_kernel(
    const int* __restrict__ src, const int* __restrict__ dst,
    const float* __restrict__ base_w, const float* __restrict__ rr,
    const int* __restrict__ row_ptr, int* __restrict__ fill,
    int2* __restrict__ recs, int E) {
    for (int e = blockIdx.x * blockDim.x + threadIdx.x; e < E;
         e += gridDim.x * blockDim.x) {
        int s = src[e], d = dst[e];
        int pos = row_ptr[d] + atomicAdd(&fill[d], 1);
        float rs = 1.f / (1.f + __expf(-rr[s]));
        float rd = 1.f / (1.f + __expf(-rr[d]));
        float c = base_w[e] * rs * rd;
        recs[pos] = make_int2(s, __float_as_int(c));
    }
}

// MFMA gate projection: [a | b] = h @ gw1 (64x128); ahb = [bf16 a | bf16 h],
// bbuf = fp32 b. Block = 64 rows, wave = 16.
__global__ __launch_bounds__(256) void gateproj_kernel(
    const float* __restrict__ h, const ushort_t* __restrict__ g1f,
    const float* __restrict__ gb1, ushort_t* __restrict__ ahb,
    float* __restrict__ bbuf, int N) {
    __shared__ ushort_t hls[4][16][72];
    const int tid  = threadIdx.x;
    const int lane = tid & 63;
    const int w    = tid >> 6;
    const int m_   = lane & 15;
    const int g    = lane >> 4;
    const int rbase = blockIdx.x * 64;
    for (int p = tid; p < 64 * 32; p += 256) {
        int row = p >> 5, c2 = p & 31;
        int grow = rbase + row;
        float2 v = (grow < N) ? *(const float2*)(h + (size_t)grow * 64 + c2 * 2)
                              : make_float2(0.f, 0.f);
        unsigned int pk = (unsigned int)f2bf(v.x) | ((unsigned int)f2bf(v.y) << 16);
        *(unsigned int*)&hls[row >> 4][row & 15][c2 * 2] = pk;
    }
    __syncthreads();
    f32x4 acc[8] = {{0,0,0,0},{0,0,0,0},{0,0,0,0},{0,0,0,0},
                    {0,0,0,0},{0,0,0,0},{0,0,0,0},{0,0,0,0}};
    #pragma unroll
    for (int kb = 0; kb < 2; ++kb) {
        bf16x8 a = *(const bf16x8*)&hls[w][m_][kb * 32 + g * 8];
        #pragma unroll
        for (int j = 0; j < 8; ++j) {
            bf16x8 b = *(const bf16x8*)(g1f + (((size_t)j * 2 + kb) * 64 + lane) * 8);
            acc[j] = __builtin_amdgcn_mfma_f32_16x16x32_bf16(a, b, acc[j], 0, 0, 0);
        }
    }
    #pragma unroll
    for (int nt = 0; nt < 4; ++nt) {
        float gbl = gb1[nt * 16 + m_];
        #pragma unroll
        for (int r = 0; r < 4; ++r) {
            int grow = rbase + w * 16 + g * 4 + r;
            if (grow < N) {
                ahb[(size_t)grow * 128 + nt * 16 + m_] = f2bf(acc[nt][r] + gbl);
                bbuf[(size_t)grow * 64 + nt * 16 + m_] = acc[nt + 4][r];
            }
        }
    }
    for (int p = tid; p < 64 * 16; p += 256) {
        int row = p >> 4, c4 = p & 15;
        int grow = rbase + row;
        if (grow < N)
            *(ushort4*)(ahb + (size_t)grow * 128 + 64 + c4 * 4) =
                *(const ushort4*)&hls[row >> 4][row & 15][c4 * 4];
    }
}

// fused gate + aggregation (R12, proven): wave-per-node, 16-lane group/edge.
__global__ __launch_bounds__(256) void gateagg_kernel(
    const int* __restrict__ row_ptr, const int2* __restrict__ recs,
    const ushort_t* __restrict__ ahb, const float* __restrict__ bb,
    const float* __restrict__ gw2, const float* __restrict__ gb2,
    float* __restrict__ m, float* __restrict__ deg, int N) {
    const int lane = threadIdx.x & 63;
    const int sub  = lane & 15;
    const int grp  = lane >> 4;
    const float4 gv = ((const float4*)gw2)[sub];
    const float gb = gb2[0];
    const int wid  = blockIdx.x * (blockDim.x >> 6) + (threadIdx.x >> 6);
    const int nw   = gridDim.x * (blockDim.x >> 6);
    for (int n = wid; n < N; n += nw) {
        const int beg = row_ptr[n], end = row_ptr[n + 1];
        const float4 bv = *(const float4*)(bb + (size_t)n * 64 + sub * 4);
        float m0 = 0.f, m1 = 0.f, m2 = 0.f, m3 = 0.f, dacc = 0.f;
        int i = beg + grp;
        for (; i + 4 < end; i += 8) {
            int2 rA = recs[i];
            int2 rB = recs[i + 4];
            const ushort_t* rowA = ahb + (size_t)rA.x * 128;
            const ushort_t* rowB = ahb + (size_t)rB.x * 128;
            ushort4 avA = *(const ushort4*)(rowA + sub * 4);
            ushort4 hvA = *(const ushort4*)(rowA + 64 + sub * 4);
            ushort4 avB = *(const ushort4*)(rowB + sub * 4);
            ushort4 hvB = *(const ushort4*)(rowB + 64 + sub * 4);
            float tA = fmaxf(bf2f(avA.x) + bv.x, 0.f) * gv.x
                     + fmaxf(bf2f(avA.y) + bv.y, 0.f) * gv.y
                     + fmaxf(bf2f(avA.z) + bv.z, 0.f) * gv.z
                     + fmaxf(bf2f(avA.w) + bv.w, 0.f) * gv.w;
            float tB = fmaxf(bf2f(avB.x) + bv.x, 0.f) * gv.x
                     + fmaxf(bf2f(avB.y) + bv.y, 0.f) * gv.y
                     + fmaxf(bf2f(avB.z) + bv.z, 0.f) * gv.z
                     + fmaxf(bf2f(avB.w) + bv.w, 0.f) * gv.w;
            #pragma unroll
            for (int o = 8; o > 0; o >>= 1) {
                tA += __shfl_xor(tA, o, 64);
                tB += __shfl_xor(tB, o, 64);
            }
            float wA = __int_as_float(rA.y) / (1.f + __expf(-(tA + gb)));
            float wB = __int_as_float(rB.y) / (1.f + __expf(-(tB + gb)));
            m0 = fmaf(wA, bf2f(hvA.x), m0); m0 = fmaf(wB, bf2f(hvB.x), m0);
            m1 = fmaf(wA, bf2f(hvA.y), m1); m1 = fmaf(wB, bf2f(hvB.y), m1);
            m2 = fmaf(wA, bf2f(hvA.z), m2); m2 = fmaf(wB, bf2f(hvB.z), m2);
            m3 = fmaf(wA, bf2f(hvA.w), m3); m3 = fmaf(wB, bf2f(hvB.w), m3);
            dacc += wA + wB;
        }
        if (i < end) {
            int2 r = recs[i];
            const ushort_t* row = ahb + (size_t)r.x * 128;
            ushort4 av = *(const ushort4*)(row + sub * 4);
            ushort4 hv = *(const ushort4*)(row + 64 + sub * 4);
            float t = fmaxf(bf2f(av.x) + bv.x, 0.f) * gv.x
                    + fmaxf(bf2f(av.y) + bv.y, 0.f) * gv.y
                    + fmaxf(bf2f(av.z) + bv.z, 0.f) * gv.z
                    + fmaxf(bf2f(av.w) + bv.w, 0.f) * gv.w;
            #pragma unroll
            for (int o = 8; o > 0; o >>= 1) t += __shfl_xor(t, o, 64);
            float w = __int_as_float(r.y) / (1.f + __expf(-(t + gb)));
            m0 = fmaf(w, bf2f(hv.x), m0);
            m1 = fmaf(w, bf2f(hv.y), m1);
            m2 = fmaf(w, bf2f(hv.z), m2);
            m3 = fmaf(w, bf2f(hv.w), m3);
            dacc += w;
        }
        #pragma unroll
        for (int o = 16; o < 64; o <<= 1) {
            m0 += __shfl_xor(m0, o, 64);
            m1 += __shfl_xor(m1, o, 64);
            m2 += __shfl_xor(m2, o, 64);
            m3 += __shfl_xor(m3, o, 64);
            dacc += __shfl_xor(dacc, o, 64);
        }
        if (lane < 16) {
            *(float4*)(m + (size_t)n * 64 + sub * 4) = make_float4(m0, m1, m2, m3);
            if (lane == 0) deg[n] = dacc;
        }
    }
}

// MFMA update + residual + LayerNorm. Block = 64 rows, wave = 16.
__global__ __launch_bounds__(256) void upd_kernel(
    const float* __restrict__ m, const float* __restrict__ deg,
    const float* __restrict__ h_in,
    const ushort_t* __restrict__ u1f, const float* __restrict__ b1,
    const ushort_t* __restrict__ u2f, const float* __restrict__ b2,
    const float* __restrict__ lng, const float* __restrict__ lnb,
    float* __restrict__ h_out, int N) {
    __shared__ ushort_t mls[4][16][72];
    __shared__ ushort_t tls[4][16][72];
    const int tid  = threadIdx.x;
    const int lane = tid & 63;
    const int w    = tid >> 6;
    const int m_   = lane & 15;
    const int g    = lane >> 4;
    const int rbase = blockIdx.x * 64;
    for (int p = tid; p < 64 * 32; p += 256) {
        int row = p >> 5, c2 = p & 31;
        int grow = rbase + row;
        float2 v = make_float2(0.f, 0.f);
        if (grow < N) {
            float dg = deg[grow] + 1e-8f;
            float2 mv = *(const float2*)(m + (size_t)grow * 64 + c2 * 2);
            v = make_float2(mv.x / dg, mv.y / dg);
        }
        unsigned int pk = (unsigned int)f2bf(v.x) | ((unsigned int)f2bf(v.y) << 16);
        *(unsigned int*)&mls[row >> 4][row & 15][c2 * 2] = pk;
    }
    __syncthreads();
    f32x4 acc[4] = {{0,0,0,0},{0,0,0,0},{0,0,0,0},{0,0,0,0}};
    #pragma unroll
    for (int kb = 0; kb < 2; ++kb) {
        bf16x8 a = *(const bf16x8*)&mls[w][m_][kb * 32 + g * 8];
        #pragma unroll
        for (int nt = 0; nt < 4; ++nt) {
            bf16x8 b = *(const bf16x8*)(u1f + (((size_t)nt * 2 + kb) * 64 + lane) * 8);
            acc[nt] = __builtin_amdgcn_mfma_f32_16x16x32_bf16(a, b, acc[nt], 0, 0, 0);
        }
    }
    #pragma unroll
    for (int nt = 0; nt < 4; ++nt) {
        float bb1 = b1[nt * 16 + m_];
        #pragma unroll
        for (int r = 0; r < 4; ++r)
            tls[w][g * 4 + r][nt * 16 + m_] = f2bf(fmaxf(acc[nt][r] + bb1, 0.f));
    }
    f32x4 acc2[4] = {{0,0,0,0},{0,0,0,0},{0,0,0,0},{0,0,0,0}};
    #pragma unroll
    for (int kb = 0; kb < 2; ++kb) {
        bf16x8 a2 = *(const bf16x8*)&tls[w][m_][kb * 32 + g * 8];
        #pragma unroll
        for (int nt = 0; nt < 4; ++nt) {
            bf16x8 b = *(const bf16x8*)(u2f + (((size_t)nt * 2 + kb) * 64 + lane) * 8);
            acc2[nt] = __builtin_amdgcn_mfma_f32_16x16x32_bf16(a2, b, acc2[nt], 0, 0, 0);
        }
    }
    #pragma unroll
    for (int r = 0; r < 4; ++r) {
        const int grow = rbase + w * 16 + g * 4 + r;
        float pre[4];
        float s1 = 0.f, s2 = 0.f;
        #pragma unroll
        for (int nt = 0; nt < 4; ++nt) {
            float hv = (grow < N) ? h_in[(size_t)grow * 64 + nt * 16 + m_] : 0.f;
            pre[nt] = acc2[nt][r] + b2[nt * 16 + m_] + hv;
            s1 += pre[nt];
            s2 += pre[nt] * pre[nt];
        }
        #pragma unroll
        for (int o = 1; o < 16; o <<= 1) {
            s1 += __shfl_xor(s1, o, 64);
            s2 += __shfl_xor(s2, o, 64);
        }
        float mean = s1 * (1.0f / 64.0f);
        float var  = s2 * (1.0f / 64.0f) - mean * mean;
        float rinv = rsqrtf(var + 1e-5f);
        if (grow < N) {
            #pragma unroll
            for (int nt = 0; nt < 4; ++nt)
                h_out[(size_t)grow * 64 + nt * 16 + m_] =
                    (pre[nt] - mean) * rinv * lng[nt * 16 + m_] + lnb[nt * 16 + m_];
        }
    }
}

// U = softplus(h @ toU_w + toU_b), K=32
__global__ __launch_bounds__(256) void out_kernel(
    const float* __restrict__ h, const float* __restrict__ tw,
    const float* __restrict__ tb, float* __restrict__ U, int N) {
    int gid = blockIdx.x * blockDim.x + threadIdx.x;
    int n = gid >> 5;
    int k = gid & 31;
    if (n >= N) return;
    float acc = tb[k];
    const float* hr = h + (size_t)n * 64;
    #pragma unroll 8
    for (int j = 0; j < 64; ++j) acc = fmaf(hr[j], tw[j * 32 + k], acc);
    float sp = acc > 0.f ? acc + log1pf(__expf(-acc)) : log1pf(__expf(acc));
    U[(size_t)n * 32 + k] = sp;
}

extern "C" void kernel_launch(void* const* d_in, const int* in_sizes, int n_in,
                              void* d_out, int out_size, void* d_ws, size_t ws_size,
                              hipStream_t stream) {
    const float* x       = (const float*)d_in[0];
    const int*   src     = (const int*)d_in[1];
    const int*   dst     = (const int*)d_in[2];
    const float* base_w  = (const float*)d_in[3];
    const float* enc_w1  = (const float*)d_in[4];
    const float* enc_b1  = (const float*)d_in[5];
    const float* enc_w2  = (const float*)d_in[6];
    const float* enc_b2  = (const float*)d_in[7];
    const float* gate_w1 = (const float*)d_in[8];
    const float* gate_b1 = (const float*)d_in[9];
    const float* gate_w2 = (const float*)d_in[10];
    const float* gate_b2 = (const float*)d_in[11];
    const float* upd_w1  = (const float*)d_in[12];
    const float* upd_b1  = (const float*)d_in[13];
    const float* upd_w2  = (const float*)d_in[14];
    const float* upd_b2  = (const float*)d_in[15];
    const float* ln_g    = (const float*)d_in[16];
    const float* ln_b    = (const float*)d_in[17];
    const float* rho_raw = (const float*)d_in[18];
    const float* toU_w   = (const float*)d_in[19];
    const float* toU_b   = (const float*)d_in[20];

    const int N = in_sizes[18];          // 50000
    const int E = in_sizes[1];           // 800000
    const int L = 2;
    const int nsb = (N + 255) / 256;     // scan blocks (196)

    // workspace layout (float units)
    float* ws  = (float*)d_ws;
    size_t off = 0;
    float* h0  = ws + off; off += (size_t)N * 64;
    float* h1  = ws + off; off += (size_t)N * 64;
    ushort_t* ahb = (ushort_t*)(ws + off); off += (size_t)N * 64;  // N*128 ushort
    float* bb  = ws + off; off += (size_t)N * 64;
    float* m   = ws + off; off += (size_t)N * 64;
    float* deg = ws + off; off += (size_t)((N + 3) & ~3);
    int* row_ptr = (int*)(ws + off); off += (size_t)((N + 1 + 3) & ~3);
    int* cnt     = (int*)(ws + off); off += (size_t)((N + 3) & ~3);
    int* bsum    = (int*)(ws + off); off += (size_t)((nsb + 3) & ~3);
    int2* recs   = (int2*)(ws + off); off += (size_t)E * 2;   // (s,c)
    ushort_t* w1f = (ushort_t*)(ws + off); off += 8192;       // 16384 ushort
    ushort_t* w2f = (ushort_t*)(ws + off); off += 2048;       // 4096 ushort
    ushort_t* g1f = (ushort_t*)(ws + off); off += 4096;       // 8192 ushort
    ushort_t* u1f = (ushort_t*)(ws + off); off += 4096;       // 8192 ushort
    ushort_t* u2f = (ushort_t*)(ws + off); off += 4096;       // 8192 ushort

    pack_kernel<<<64, 256, 0, stream>>>(enc_w1, enc_w2, gate_w1, upd_w1, upd_w2,
                                        w1f, w2f, g1f, u1f, u2f);
    enc_kernel<<<(N + 63) / 64, 256, 0, stream>>>(x, w1f, enc_b1, w2f, enc_b2,
                                                  h0, N);

    // CSR build with hierarchical scan; rho folded into scatter
    hipMemsetAsync(cnt, 0, (size_t)N * sizeof(int), stream);
    hist_kernel<<<(E + 255) / 256, 256, 0, stream>>>(dst, cnt, E);
    scan1_kernel<<<nsb, 256, 0, stream>>>(cnt, bsum, N);
    scan2_kernel<<<1, 1024, 0, stream>>>(bsum, nsb);
    scan3_kernel<<<nsb, 256, 0, stream>>>(cnt, bsum, row_ptr, N);
    hipMemsetAsync(cnt, 0, (size_t)N * sizeof(int), stream);
    scatter_kernel<<<(E + 255) / 256, 256, 0, stream>>>(src, dst, base_w, rho_raw,
                                                        row_ptr, cnt, recs, E);

    const int nblk64 = (N + 63) / 64;
    float* h_cur = h0;
    float* h_nxt = h1;
    for (int l = 0; l < L; ++l) {
        gateproj_kernel<<<nblk64, 256, 0, stream>>>(h_cur, g1f, gate_b1,
                                                    ahb, bb, N);
        gateagg_kernel<<<2048, 256, 0, stream>>>(row_ptr, recs, ahb, bb,
                                                 gate_w2, gate_b2, m, deg, N);
        upd_kernel<<<nblk64, 256, 0, stream>>>(
            m, deg, h_cur,
            u1f + (size_t)l * 4096, upd_b1 + l * 64,
            u2f + (size_t)l * 4096, upd_b2 + l * 64,
            ln_g + l * 64, ln_b + l * 64, h_nxt, N);
        float* tf = h_cur; h_cur = h_nxt; h_nxt = tf;
    }

    out_kernel<<<((N * 32) + 255) / 256, 256, 0, stream>>>(h_cur, toU_w, toU_b,
                                                           (float*)d_out, N);
}

// Round 16
// 262.892 us; speedup vs baseline: 2.6067x; 1.0284x over previous
//
#include <hip/hip_runtime.h>
#include <math.h>

// ---------------------------------------------------------------------------
// StageA GNN: pack -> MFMA-enc -> CSR(parallel scan, XCD-partitioned scatter)
// -> L x (MFMA-gateproj, gateagg, MFMA-upd) -> head.
// R16: (a) scatter partitioned by assumed XCD (blockIdx&7) over dst ranges so
// each CSR cache line is written by ONE XCD (kills the 8x write amplification
// from cross-XCD L2 partial-line evictions; wrong mapping = perf-neutral);
// (b) enc x-staging widened to float4 (16B/lane). All else = proven R15.
// ---------------------------------------------------------------------------

typedef unsigned short ushort_t;
typedef __attribute__((ext_vector_type(8))) short bf16x8;
typedef __attribute__((ext_vector_type(4))) float f32x4;

__device__ __forceinline__ float bf2f(ushort_t u) {
    return __uint_as_float(((unsigned int)u) << 16);
}
__device__ __forceinline__ ushort_t f2bf(float f) {
    unsigned int x = __float_as_uint(f);
    unsigned int lsb = (x >> 16) & 1u;
    x += 0x7fffu + lsb;                 // round-to-nearest-even
    return (ushort_t)(x >> 16);
}

// pack all GEMV/GEMM weights into MFMA B-fragment order (bf16).
__global__ __launch_bounds__(256) void pack_kernel(
    const float* __restrict__ w1, const float* __restrict__ w2,
    const float* __restrict__ gw1, const float* __restrict__ uw1,
    const float* __restrict__ uw2,
    ushort_t* __restrict__ w1f, ushort_t* __restrict__ w2f,
    ushort_t* __restrict__ g1f, ushort_t* __restrict__ u1f,
    ushort_t* __restrict__ u2f) {
    int t = blockIdx.x * 256 + threadIdx.x;
    if (t < 16384) {   // w1f: nt(4) kb(8) lane(64) i(8)
        int i = t & 7, l = (t >> 3) & 63, kb = (t >> 9) & 7, nt = t >> 12;
        int k = kb * 32 + (l >> 4) * 8 + i, n = nt * 16 + (l & 15);
        w1f[t] = f2bf(w1[(size_t)k * 64 + n]);
    }
    if (t < 4096) {    // w2f: nt(4) kb(2)
        int i = t & 7, l = (t >> 3) & 63, kb = (t >> 9) & 1, nt = t >> 10;
        int k = kb * 32 + (l >> 4) * 8 + i, n = nt * 16 + (l & 15);
        w2f[t] = f2bf(w2[(size_t)k * 64 + n]);
    }
    if (t < 8192) {    // g1f: j(8)=part*4+nt, kb(2); gw1 is [128][64]
        int i = t & 7, l = (t >> 3) & 63, kb = (t >> 9) & 1, j = t >> 10;
        int part = j >> 2, nt = j & 3;
        int k = part * 64 + kb * 32 + (l >> 4) * 8 + i, n = nt * 16 + (l & 15);
        g1f[t] = f2bf(gw1[(size_t)k * 64 + n]);
    }
    if (t < 8192) {    // u1f/u2f: layer(2) nt(4) kb(2)
        int i = t & 7, l = (t >> 3) & 63, kb = (t >> 9) & 1;
        int nt = (t >> 10) & 3, lay = t >> 12;
        int k = kb * 32 + (l >> 4) * 8 + i, n = nt * 16 + (l & 15);
        u1f[t] = f2bf(uw1[(size_t)lay * 4096 + (size_t)k * 64 + n]);
        u2f[t] = f2bf(uw2[(size_t)lay * 4096 + (size_t)k * 64 + n]);
    }
}

// MFMA encoder: h = relu(relu(x@W1+b1)@W2+b2), block = 64 rows, wave = 16.
// R16: float4 x-staging (16B/lane).
__global__ __launch_bounds__(256) void enc_kernel(
    const float* __restrict__ x, const ushort_t* __restrict__ w1f,
    const float* __restrict__ b1, const ushort_t* __restrict__ w2f,
    const float* __restrict__ b2, float* __restrict__ h, int N) {
    __shared__ ushort_t xls[4][16][264];
    __shared__ ushort_t tls[4][16][72];
    const int tid  = threadIdx.x;
    const int lane = tid & 63;
    const int w    = tid >> 6;
    const int m    = lane & 15;
    const int g    = lane >> 4;
    const int rbase = blockIdx.x * 64;
    for (int p = tid; p < 64 * 64; p += 256) {
        int row = p >> 6, k4 = p & 63;
        int grow = rbase + row;
        float4 v = (grow < N) ? *(const float4*)(x + (size_t)grow * 256 + k4 * 4)
                              : make_float4(0.f, 0.f, 0.f, 0.f);
        unsigned int p0 = (unsigned int)f2bf(v.x) | ((unsigned int)f2bf(v.y) << 16);
        unsigned int p1 = (unsigned int)f2bf(v.z) | ((unsigned int)f2bf(v.w) << 16);
        *(uint2*)&xls[row >> 4][row & 15][k4 * 4] = make_uint2(p0, p1);
    }
    __syncthreads();
    f32x4 acc[4] = {{0,0,0,0},{0,0,0,0},{0,0,0,0},{0,0,0,0}};
    #pragma unroll
    for (int kb = 0; kb < 8; ++kb) {
        bf16x8 a = *(const bf16x8*)&xls[w][m][kb * 32 + g * 8];
        #pragma unroll
        for (int nt = 0; nt < 4; ++nt) {
            bf16x8 b = *(const bf16x8*)(w1f + (((size_t)nt * 8 + kb) * 64 + lane) * 8);
            acc[nt] = __builtin_amdgcn_mfma_f32_16x16x32_bf16(a, b, acc[nt], 0, 0, 0);
        }
    }
    #pragma unroll
    for (int nt = 0; nt < 4; ++nt) {
        float bb1 = b1[nt * 16 + m];
        #pragma unroll
        for (int r = 0; r < 4; ++r) {
            float tv = fmaxf(acc[nt][r] + bb1, 0.f);
            tls[w][g * 4 + r][nt * 16 + m] = f2bf(tv);
        }
    }
    f32x4 acc2[4] = {{0,0,0,0},{0,0,0,0},{0,0,0,0},{0,0,0,0}};
    #pragma unroll
    for (int kb = 0; kb < 2; ++kb) {
        bf16x8 a2 = *(const bf16x8*)&tls[w][m][kb * 32 + g * 8];
        #pragma unroll
        for (int nt = 0; nt < 4; ++nt) {
            bf16x8 b = *(const bf16x8*)(w2f + (((size_t)nt * 2 + kb) * 64 + lane) * 8);
            acc2[nt] = __builtin_amdgcn_mfma_f32_16x16x32_bf16(a2, b, acc2[nt], 0, 0, 0);
        }
    }
    #pragma unroll
    for (int nt = 0; nt < 4; ++nt) {
        float bb2 = b2[nt * 16 + m];
        #pragma unroll
        for (int r = 0; r < 4; ++r) {
            int grow = rbase + w * 16 + g * 4 + r;
            if (grow < N)
                h[(size_t)grow * 64 + nt * 16 + m] = fmaxf(acc2[nt][r] + bb2, 0.f);
        }
    }
}

// ---- CSR build ----
__global__ __launch_bounds__(256) void hist_kernel(
    const int* __restrict__ dst, int* __restrict__ cnt, int E) {
    for (int e = blockIdx.x * blockDim.x + threadIdx.x; e < E;
         e += gridDim.x * blockDim.x)
        atomicAdd(&cnt[dst[e]], 1);
}

// 3-phase hierarchical exclusive scan of cnt[N] -> row_ptr[N+1]
__global__ __launch_bounds__(256) void scan1_kernel(
    const int* __restrict__ cnt, int* __restrict__ bsum, int N) {
    __shared__ int red[256];
    int i = blockIdx.x * 256 + threadIdx.x;
    red[threadIdx.x] = (i < N) ? cnt[i] : 0;
    __syncthreads();
    for (int off = 128; off > 0; off >>= 1) {
        if (threadIdx.x < off) red[threadIdx.x] += red[threadIdx.x + off];
        __syncthreads();
    }
    if (threadIdx.x == 0) bsum[blockIdx.x] = red[0];
}

__global__ __launch_bounds__(1024) void scan2_kernel(
    int* __restrict__ bsum, int nb) {
    __shared__ int s[1024];
    int v = (threadIdx.x < nb) ? bsum[threadIdx.x] : 0;
    s[threadIdx.x] = v;
    __syncthreads();
    for (int off = 1; off < 1024; off <<= 1) {
        int t = (threadIdx.x >= off) ? s[threadIdx.x - off] : 0;
        __syncthreads();
        s[threadIdx.x] += t;
        __syncthreads();
    }
    if (threadIdx.x < nb) bsum[threadIdx.x] = s[threadIdx.x] - v;  // exclusive
}

__global__ __launch_bounds__(256) void scan3_kernel(
    const int* __restrict__ cnt, const int* __restrict__ bsum,
    int* __restrict__ row_ptr, int N) {
    __shared__ int s[256];
    int i = blockIdx.x * 256 + threadIdx.x;
    int v = (i < N) ? cnt[i] : 0;
    s[threadIdx.x] = v;
    __syncthreads();
    for (int off = 1; off < 256; off <<= 1) {
        int t = (threadIdx.x >= off) ? s[threadIdx.x - off] : 0;
        __syncthreads();
        s[threadIdx.x] += t;
        __syncthreads();
    }
    if (i < N) row_ptr[i] = bsum[blockIdx.x] + s[threadIdx.x] - v;  // exclusive
    if (i == N - 1) row_ptr[N] = bsum[blockIdx.x] + s[threadIdx.x]; // total
}

// XCD-partitioned scatter: block's assumed XCD (blockIdx&7) handles only
// dst in [xcd*N/8, (xcd+1)*N/8) -> every recs cache line written by ONE XCD.
__global__ __launch_bounds__(256) void scatter_kernel(
    const int* __restrict__ src, const int* __restrict__ dst,
    const float* __restrict__ base_w, const float* __restrict__ rr,
    const int* __restrict__ row_ptr, int* __restrict__ fill,
    int2* __restrict__ recs, int N, int E) {
    const int xcd  = blockIdx.x & 7;
    const int grpb = gridDim.x >> 3;          // blocks per XCD-group
    const int gb   = blockIdx.x >> 3;
    const int dlo = (int)(((long long)N * xcd) >> 3);
    const int dhi = (int)(((long long)N * (xcd + 1)) >> 3);
    for (int e = gb * blockDim.x + threadIdx.x; e < E;
         e += grpb * blockDim.x) {
        int d = dst[e];
        if (d < dlo || d >= dhi) continue;
        int s = src[e];
        int pos = row_ptr[d] + atomicAdd(&fill[d], 1);
        float rs = 1.f / (1.f + __expf(-rr[s]));
        float rd = 1.f / (1.f + __expf(-rr[d]));
        float c = base_w[e] * rs * rd;
        recs[pos] = make_int2(s, __float_as_int(c));
    }
}

// MFMA gate projection: [a | b] = h @ gw1 (64x128); ahb = [bf16 a | bf16 h],
// bbuf = fp32 b. Block = 64 rows, wave = 16.
__global__ __launch_bounds__(256) void gateproj_kernel(
    const float* __restrict__ h, const ushort_t* __restrict__ g1f,
    const float* __restrict__ gb1, ushort_t* __restrict__ ahb,
    float* __restrict__ bbuf, int N) {
    __shared__ ushort_t hls[4][16][72];
    const int tid  = threadIdx.x;
    const int lane = tid & 63;
    const int w    = tid >> 6;
    const int m_   = lane & 15;
    const int g    = lane >> 4;
    const int rbase = blockIdx.x * 64;
    for (int p = tid; p < 64 * 32; p += 256) {
        int row = p >> 5, c2 = p & 31;
        int grow = rbase + row;
        float2 v = (grow < N) ? *(const float2*)(h + (size_t)grow * 64 + c2 * 2)
                              : make_float2(0.f, 0.f);
        unsigned int pk = (unsigned int)f2bf(v.x) | ((unsigned int)f2bf(v.y) << 16);
        *(unsigned int*)&hls[row >> 4][row & 15][c2 * 2] = pk;
    }
    __syncthreads();
    f32x4 acc[8] = {{0,0,0,0},{0,0,0,0},{0,0,0,0},{0,0,0,0},
                    {0,0,0,0},{0,0,0,0},{0,0,0,0},{0,0,0,0}};
    #pragma unroll
    for (int kb = 0; kb < 2; ++kb) {
        bf16x8 a = *(const bf16x8*)&hls[w][m_][kb * 32 + g * 8];
        #pragma unroll
        for (int j = 0; j < 8; ++j) {
            bf16x8 b = *(const bf16x8*)(g1f + (((size_t)j * 2 + kb) * 64 + lane) * 8);
            acc[j] = __builtin_amdgcn_mfma_f32_16x16x32_bf16(a, b, acc[j], 0, 0, 0);
        }
    }
    #pragma unroll
    for (int nt = 0; nt < 4; ++nt) {
        float gbl = gb1[nt * 16 + m_];
        #pragma unroll
        for (int r = 0; r < 4; ++r) {
            int grow = rbase + w * 16 + g * 4 + r;
            if (grow < N) {
                ahb[(size_t)grow * 128 + nt * 16 + m_] = f2bf(acc[nt][r] + gbl);
                bbuf[(size_t)grow * 64 + nt * 16 + m_] = acc[nt + 4][r];
            }
        }
    }
    for (int p = tid; p < 64 * 16; p += 256) {
        int row = p >> 4, c4 = p & 15;
        int grow = rbase + row;
        if (grow < N)
            *(ushort4*)(ahb + (size_t)grow * 128 + 64 + c4 * 4) =
                *(const ushort4*)&hls[row >> 4][row & 15][c4 * 4];
    }
}

// fused gate + aggregation (R12, proven): wave-per-node, 16-lane group/edge.
__global__ __launch_bounds__(256) void gateagg_kernel(
    const int* __restrict__ row_ptr, const int2* __restrict__ recs,
    const ushort_t* __restrict__ ahb, const float* __restrict__ bb,
    const float* __restrict__ gw2, const float* __restrict__ gb2,
    float* __restrict__ m, float* __restrict__ deg, int N) {
    const int lane = threadIdx.x & 63;
    const int sub  = lane & 15;
    const int grp  = lane >> 4;
    const float4 gv = ((const float4*)gw2)[sub];
    const float gb = gb2[0];
    const int wid  = blockIdx.x * (blockDim.x >> 6) + (threadIdx.x >> 6);
    const int nw   = gridDim.x * (blockDim.x >> 6);
    for (int n = wid; n < N; n += nw) {
        const int beg = row_ptr[n], end = row_ptr[n + 1];
        const float4 bv = *(const float4*)(bb + (size_t)n * 64 + sub * 4);
        float m0 = 0.f, m1 = 0.f, m2 = 0.f, m3 = 0.f, dacc = 0.f;
        int i = beg + grp;
        for (; i + 4 < end; i += 8) {
            int2 rA = recs[i];
            int2 rB = recs[i + 4];
            const ushort_t* rowA = ahb + (size_t)rA.x * 128;
            const ushort_t* rowB = ahb + (size_t)rB.x * 128;
            ushort4 avA = *(const ushort4*)(rowA + sub * 4);
            ushort4 hvA = *(const ushort4*)(rowA + 64 + sub * 4);
            ushort4 avB = *(const ushort4*)(rowB + sub * 4);
            ushort4 hvB = *(const ushort4*)(rowB + 64 + sub * 4);
            float tA = fmaxf(bf2f(avA.x) + bv.x, 0.f) * gv.x
                     + fmaxf(bf2f(avA.y) + bv.y, 0.f) * gv.y
                     + fmaxf(bf2f(avA.z) + bv.z, 0.f) * gv.z
                     + fmaxf(bf2f(avA.w) + bv.w, 0.f) * gv.w;
            float tB = fmaxf(bf2f(avB.x) + bv.x, 0.f) * gv.x
                     + fmaxf(bf2f(avB.y) + bv.y, 0.f) * gv.y
                     + fmaxf(bf2f(avB.z) + bv.z, 0.f) * gv.z
                     + fmaxf(bf2f(avB.w) + bv.w, 0.f) * gv.w;
            #pragma unroll
            for (int o = 8; o > 0; o >>= 1) {
                tA += __shfl_xor(tA, o, 64);
                tB += __shfl_xor(tB, o, 64);
            }
            float wA = __int_as_float(rA.y) / (1.f + __expf(-(tA + gb)));
            float wB = __int_as_float(rB.y) / (1.f + __expf(-(tB + gb)));
            m0 = fmaf(wA, bf2f(hvA.x), m0); m0 = fmaf(wB, bf2f(hvB.x), m0);
            m1 = fmaf(wA, bf2f(hvA.y), m1); m1 = fmaf(wB, bf2f(hvB.y), m1);
            m2 = fmaf(wA, bf2f(hvA.z), m2); m2 = fmaf(wB, bf2f(hvB.z), m2);
            m3 = fmaf(wA, bf2f(hvA.w), m3); m3 = fmaf(wB, bf2f(hvB.w), m3);
            dacc += wA + wB;
        }
        if (i < end) {
            int2 r = recs[i];
            const ushort_t* row = ahb + (size_t)r.x * 128;
            ushort4 av = *(const ushort4*)(row + sub * 4);
            ushort4 hv = *(const ushort4*)(row + 64 + sub * 4);
            float t = fmaxf(bf2f(av.x) + bv.x, 0.f) * gv.x
                    + fmaxf(bf2f(av.y) + bv.y, 0.f) * gv.y
                    + fmaxf(bf2f(av.z) + bv.z, 0.f) * gv.z
                    + fmaxf(bf2f(av.w) + bv.w, 0.f) * gv.w;
            #pragma unroll
            for (int o = 8; o > 0; o >>= 1) t += __shfl_xor(t, o, 64);
            float w = __int_as_float(r.y) / (1.f + __expf(-(t + gb)));
            m0 = fmaf(w, bf2f(hv.x), m0);
            m1 = fmaf(w, bf2f(hv.y), m1);
            m2 = fmaf(w, bf2f(hv.z), m2);
            m3 = fmaf(w, bf2f(hv.w), m3);
            dacc += w;
        }
        #pragma unroll
        for (int o = 16; o < 64; o <<= 1) {
            m0 += __shfl_xor(m0, o, 64);
            m1 += __shfl_xor(m1, o, 64);
            m2 += __shfl_xor(m2, o, 64);
            m3 += __shfl_xor(m3, o, 64);
            dacc += __shfl_xor(dacc, o, 64);
        }
        if (lane < 16) {
            *(float4*)(m + (size_t)n * 64 + sub * 4) = make_float4(m0, m1, m2, m3);
            if (lane == 0) deg[n] = dacc;
        }
    }
}

// MFMA update + residual + LayerNorm. Block = 64 rows, wave = 16.
__global__ __launch_bounds__(256) void upd_kernel(
    const float* __restrict__ m, const float* __restrict__ deg,
    const float* __restrict__ h_in,
    const ushort_t* __restrict__ u1f, const float* __restrict__ b1,
    const ushort_t* __restrict__ u2f, const float* __restrict__ b2,
    const float* __restrict__ lng, const float* __restrict__ lnb,
    float* __restrict__ h_out, int N) {
    __shared__ ushort_t mls[4][16][72];
    __shared__ ushort_t tls[4][16][72];
    const int tid  = threadIdx.x;
    const int lane = tid & 63;
    const int w    = tid >> 6;
    const int m_   = lane & 15;
    const int g    = lane >> 4;
    const int rbase = blockIdx.x * 64;
    for (int p = tid; p < 64 * 32; p += 256) {
        int row = p >> 5, c2 = p & 31;
        int grow = rbase + row;
        float2 v = make_float2(0.f, 0.f);
        if (grow < N) {
            float dg = deg[grow] + 1e-8f;
            float2 mv = *(const float2*)(m + (size_t)grow * 64 + c2 * 2);
            v = make_float2(mv.x / dg, mv.y / dg);
        }
        unsigned int pk = (unsigned int)f2bf(v.x) | ((unsigned int)f2bf(v.y) << 16);
        *(unsigned int*)&mls[row >> 4][row & 15][c2 * 2] = pk;
    }
    __syncthreads();
    f32x4 acc[4] = {{0,0,0,0},{0,0,0,0},{0,0,0,0},{0,0,0,0}};
    #pragma unroll
    for (int kb = 0; kb < 2; ++kb) {
        bf16x8 a = *(const bf16x8*)&mls[w][m_][kb * 32 + g * 8];
        #pragma unroll
        for (int nt = 0; nt < 4; ++nt) {
            bf16x8 b = *(const bf16x8*)(u1f + (((size_t)nt * 2 + kb) * 64 + lane) * 8);
            acc[nt] = __builtin_amdgcn_mfma_f32_16x16x32_bf16(a, b, acc[nt], 0, 0, 0);
        }
    }
    #pragma unroll
    for (int nt = 0; nt < 4; ++nt) {
        float bb1 = b1[nt * 16 + m_];
        #pragma unroll
        for (int r = 0; r < 4; ++r)
            tls[w][g * 4 + r][nt * 16 + m_] = f2bf(fmaxf(acc[nt][r] + bb1, 0.f));
    }
    f32x4 acc2[4] = {{0,0,0,0},{0,0,0,0},{0,0,0,0},{0,0,0,0}};
    #pragma unroll
    for (int kb = 0; kb < 2; ++kb) {
        bf16x8 a2 = *(const bf16x8*)&tls[w][m_][kb * 32 + g * 8];
        #pragma unroll
        for (int nt = 0; nt < 4; ++nt) {
            bf16x8 b = *(const bf16x8*)(u2f + (((size_t)nt * 2 + kb) * 64 + lane) * 8);
            acc2[nt] = __builtin_amdgcn_mfma_f32_16x16x32_bf16(a2, b, acc2[nt], 0, 0, 0);
        }
    }
    #pragma unroll
    for (int r = 0; r < 4; ++r) {
        const int grow = rbase + w * 16 + g * 4 + r;
        float pre[4];
        float s1 = 0.f, s2 = 0.f;
        #pragma unroll
        for (int nt = 0; nt < 4; ++nt) {
            float hv = (grow < N) ? h_in[(size_t)grow * 64 + nt * 16 + m_] : 0.f;
            pre[nt] = acc2[nt][r] + b2[nt * 16 + m_] + hv;
            s1 += pre[nt];
            s2 += pre[nt] * pre[nt];
        }
        #pragma unroll
        for (int o = 1; o < 16; o <<= 1) {
            s1 += __shfl_xor(s1, o, 64);
            s2 += __shfl_xor(s2, o, 64);
        }
        float mean = s1 * (1.0f / 64.0f);
        float var  = s2 * (1.0f / 64.0f) - mean * mean;
        float rinv = rsqrtf(var + 1e-5f);
        if (grow < N) {
            #pragma unroll
            for (int nt = 0; nt < 4; ++nt)
                h_out[(size_t)grow * 64 + nt * 16 + m_] =
                    (pre[nt] - mean) * rinv * lng[nt * 16 + m_] + lnb[nt * 16 + m_];
        }
    }
}

// U = softplus(h @ toU_w + toU_b), K=32
__global__ __launch_bounds__(256) void out_kernel(
    const float* __restrict__ h, const float* __restrict__ tw,
    const float* __restrict__ tb, float* __restrict__ U, int N) {
    int gid = blockIdx.x * blockDim.x + threadIdx.x;
    int n = gid >> 5;
    int k = gid & 31;
    if (n >= N) return;
    float acc = tb[k];
    const float* hr = h + (size_t)n * 64;
    #pragma unroll 8
    for (int j = 0; j < 64; ++j) acc = fmaf(hr[j], tw[j * 32 + k], acc);
    float sp = acc > 0.f ? acc + log1pf(__expf(-acc)) : log1pf(__expf(acc));
    U[(size_t)n * 32 + k] = sp;
}

extern "C" void kernel_launch(void* const* d_in, const int* in_sizes, int n_in,
                              void* d_out, int out_size, void* d_ws, size_t ws_size,
                              hipStream_t stream) {
    const float* x       = (const float*)d_in[0];
    const int*   src     = (const int*)d_in[1];
    const int*   dst     = (const int*)d_in[2];
    const float* base_w  = (const float*)d_in[3];
    const float* enc_w1  = (const float*)d_in[4];
    const float* enc_b1  = (const float*)d_in[5];
    const float* enc_w2  = (const float*)d_in[6];
    const float* enc_b2  = (const float*)d_in[7];
    const float* gate_w1 = (const float*)d_in[8];
    const float* gate_b1 = (const float*)d_in[9];
    const float* gate_w2 = (const float*)d_in[10];
    const float* gate_b2 = (const float*)d_in[11];
    const float* upd_w1  = (const float*)d_in[12];
    const float* upd_b1  = (const float*)d_in[13];
    const float* upd_w2  = (const float*)d_in[14];
    const float* upd_b2  = (const float*)d_in[15];
    const float* ln_g    = (const float*)d_in[16];
    const float* ln_b    = (const float*)d_in[17];
    const float* rho_raw = (const float*)d_in[18];
    const float* toU_w   = (const float*)d_in[19];
    const float* toU_b   = (const float*)d_in[20];

    const int N = in_sizes[18];          // 50000
    const int E = in_sizes[1];           // 800000
    const int L = 2;
    const int nsb = (N + 255) / 256;     // scan blocks (196)

    // workspace layout (float units)
    float* ws  = (float*)d_ws;
    size_t off = 0;
    float* h0  = ws + off; off += (size_t)N * 64;
    float* h1  = ws + off; off += (size_t)N * 64;
    ushort_t* ahb = (ushort_t*)(ws + off); off += (size_t)N * 64;  // N*128 ushort
    float* bb  = ws + off; off += (size_t)N * 64;
    float* m   = ws + off; off += (size_t)N * 64;
    float* deg = ws + off; off += (size_t)((N + 3) & ~3);
    int* row_ptr = (int*)(ws + off); off += (size_t)((N + 1 + 3) & ~3);
    int* cnt     = (int*)(ws + off); off += (size_t)((N + 3) & ~3);
    int* bsum    = (int*)(ws + off); off += (size_t)((nsb + 3) & ~3);
    int2* recs   = (int2*)(ws + off); off += (size_t)E * 2;   // (s,c)
    ushort_t* w1f = (ushort_t*)(ws + off); off += 8192;       // 16384 ushort
    ushort_t* w2f = (ushort_t*)(ws + off); off += 2048;       // 4096 ushort
    ushort_t* g1f = (ushort_t*)(ws + off); off += 4096;       // 8192 ushort
    ushort_t* u1f = (ushort_t*)(ws + off); off += 4096;       // 8192 ushort
    ushort_t* u2f = (ushort_t*)(ws + off); off += 4096;       // 8192 ushort

    pack_kernel<<<64, 256, 0, stream>>>(enc_w1, enc_w2, gate_w1, upd_w1, upd_w2,
                                        w1f, w2f, g1f, u1f, u2f);
    enc_kernel<<<(N + 63) / 64, 256, 0, stream>>>(x, w1f, enc_b1, w2f, enc_b2,
                                                  h0, N);

    // CSR build with hierarchical scan + XCD-partitioned scatter
    hipMemsetAsync(cnt, 0, (size_t)N * sizeof(int), stream);
    hist_kernel<<<(E + 255) / 256, 256, 0, stream>>>(dst, cnt, E);
    scan1_kernel<<<nsb, 256, 0, stream>>>(cnt, bsum, N);
    scan2_kernel<<<1, 1024, 0, stream>>>(bsum, nsb);
    scan3_kernel<<<nsb, 256, 0, stream>>>(cnt, bsum, row_ptr, N);
    hipMemsetAsync(cnt, 0, (size_t)N * sizeof(int), stream);
    scatter_kernel<<<2048, 256, 0, stream>>>(src, dst, base_w, rho_raw,
                                             row_ptr, cnt, recs, N, E);

    const int nblk64 = (N + 63) / 64;
    float* h_cur = h0;
    float* h_nxt = h1;
    for (int l = 0; l < L; ++l) {
        gateproj_kernel<<<nblk64, 256, 0, stream>>>(h_cur, g1f, gate_b1,
                                                    ahb, bb, N);
        gateagg_kernel<<<2048, 256, 0, stream>>>(row_ptr, recs, ahb, bb,
                                                 gate_w2, gate_b2, m, deg, N);
        upd_kernel<<<nblk64, 256, 0, stream>>>(
            m, deg, h_cur,
            u1f + (size_t)l * 4096, upd_b1 + l * 64,
            u2f + (size_t)l * 4096, upd_b2 + l * 64,
            ln_g + l * 64, ln_b + l * 64, h_nxt, N);
        float* tf = h_cur; h_cur = h_nxt; h_nxt = tf;
    }

    out_kernel<<<((N * 32) + 255) / 256, 256, 0, stream>>>(h_cur, toU_w, toU_b,
                                                           (float*)d_out, N);
}

// Round 17
// 212.151 us; speedup vs baseline: 3.2301x; 1.2392x over previous
//
#include <hip/hip_runtime.h>
#include <math.h>

// ---------------------------------------------------------------------------
// StageA GNN: pack -> MFMA-enc(+proj0) -> CSR(rank-hist, atomic-free scatter)
// -> L x (gateagg, MFMA-upd(+proj1 | +outhead)) -> done.
// R17: (a) hist also records rank[e] -> scatter is pure streaming (no atomics,
// no partition, no refetch); (b) gate projection fused into h producers as
// MFMA epilogues (enc for layer0, upd MODE0 for layer1); (c) softplus head
// fused into upd MODE1 (writes d_out, drops final h store). Deletes 5
// dispatches + two full h round-trips vs R16.
// ---------------------------------------------------------------------------

typedef unsigned short ushort_t;
typedef __attribute__((ext_vector_type(8))) short bf16x8;
typedef __attribute__((ext_vector_type(4))) float f32x4;

__device__ __forceinline__ float bf2f(ushort_t u) {
    return __uint_as_float(((unsigned int)u) << 16);
}
__device__ __forceinline__ ushort_t f2bf(float f) {
    unsigned int x = __float_as_uint(f);
    unsigned int lsb = (x >> 16) & 1u;
    x += 0x7fffu + lsb;                 // round-to-nearest-even
    return (ushort_t)(x >> 16);
}

// pack all weights into MFMA B-fragment order (bf16).
// fragment: elem i of lane l = B[k = kb*32 + (l>>4)*8 + i][n = nt*16 + (l&15)]
__global__ __launch_bounds__(256) void pack_kernel(
    const float* __restrict__ w1, const float* __restrict__ w2,
    const float* __restrict__ gw1, const float* __restrict__ uw1,
    const float* __restrict__ uw2, const float* __restrict__ tw,
    ushort_t* __restrict__ w1f, ushort_t* __restrict__ w2f,
    ushort_t* __restrict__ g1f, ushort_t* __restrict__ u1f,
    ushort_t* __restrict__ u2f, ushort_t* __restrict__ tuf) {
    int t = blockIdx.x * 256 + threadIdx.x;
    if (t < 16384) {   // w1f: nt(4) kb(8) lane(64) i(8)
        int i = t & 7, l = (t >> 3) & 63, kb = (t >> 9) & 7, nt = t >> 12;
        int k = kb * 32 + (l >> 4) * 8 + i, n = nt * 16 + (l & 15);
        w1f[t] = f2bf(w1[(size_t)k * 64 + n]);
    }
    if (t < 4096) {    // w2f: nt(4) kb(2)
        int i = t & 7, l = (t >> 3) & 63, kb = (t >> 9) & 1, nt = t >> 10;
        int k = kb * 32 + (l >> 4) * 8 + i, n = nt * 16 + (l & 15);
        w2f[t] = f2bf(w2[(size_t)k * 64 + n]);
    }
    if (t < 8192) {    // g1f: j(8)=part*4+nt, kb(2); gw1 is [128][64]
        int i = t & 7, l = (t >> 3) & 63, kb = (t >> 9) & 1, j = t >> 10;
        int part = j >> 2, nt = j & 3;
        int k = part * 64 + kb * 32 + (l >> 4) * 8 + i, n = nt * 16 + (l & 15);
        g1f[t] = f2bf(gw1[(size_t)k * 64 + n]);
    }
    if (t < 8192) {    // u1f/u2f: layer(2) nt(4) kb(2)
        int i = t & 7, l = (t >> 3) & 63, kb = (t >> 9) & 1;
        int nt = (t >> 10) & 3, lay = t >> 12;
        int k = kb * 32 + (l >> 4) * 8 + i, n = nt * 16 + (l & 15);
        u1f[t] = f2bf(uw1[(size_t)lay * 4096 + (size_t)k * 64 + n]);
        u2f[t] = f2bf(uw2[(size_t)lay * 4096 + (size_t)k * 64 + n]);
    }
    if (t < 2048) {    // tuf: nt(2) kb(2); toU_w is [64][32]
        int i = t & 7, l = (t >> 3) & 63, kb = (t >> 9) & 1, nt = t >> 10;
        int k = kb * 32 + (l >> 4) * 8 + i, n = nt * 16 + (l & 15);
        tuf[t] = f2bf(tw[(size_t)k * 32 + n]);
    }
}

// MFMA encoder + fused layer-0 gate projection.
// h = relu(relu(x@W1+b1)@W2+b2); [a|b] = h@gw1; ahb=[bf16 a|bf16 h]; bbuf=b.
__global__ __launch_bounds__(256) void enc_kernel(
    const float* __restrict__ x, const ushort_t* __restrict__ w1f,
    const float* __restrict__ b1, const ushort_t* __restrict__ w2f,
    const float* __restrict__ b2, const ushort_t* __restrict__ g1f,
    const float* __restrict__ gb1,
    float* __restrict__ h, ushort_t* __restrict__ ahb,
    float* __restrict__ bbuf, int N) {
    __shared__ ushort_t xls[4][16][264];
    __shared__ ushort_t tls[4][16][72];
    const int tid  = threadIdx.x;
    const int lane = tid & 63;
    const int w    = tid >> 6;
    const int m    = lane & 15;
    const int g    = lane >> 4;
    const int rbase = blockIdx.x * 64;
    for (int p = tid; p < 64 * 64; p += 256) {
        int row = p >> 6, k4 = p & 63;
        int grow = rbase + row;
        float4 v = (grow < N) ? *(const float4*)(x + (size_t)grow * 256 + k4 * 4)
                              : make_float4(0.f, 0.f, 0.f, 0.f);
        unsigned int p0 = (unsigned int)f2bf(v.x) | ((unsigned int)f2bf(v.y) << 16);
        unsigned int p1 = (unsigned int)f2bf(v.z) | ((unsigned int)f2bf(v.w) << 16);
        *(uint2*)&xls[row >> 4][row & 15][k4 * 4] = make_uint2(p0, p1);
    }
    __syncthreads();
    f32x4 acc[4] = {{0,0,0,0},{0,0,0,0},{0,0,0,0},{0,0,0,0}};
    #pragma unroll
    for (int kb = 0; kb < 8; ++kb) {
        bf16x8 a = *(const bf16x8*)&xls[w][m][kb * 32 + g * 8];
        #pragma unroll
        for (int nt = 0; nt < 4; ++nt) {
            bf16x8 b = *(const bf16x8*)(w1f + (((size_t)nt * 8 + kb) * 64 + lane) * 8);
            acc[nt] = __builtin_amdgcn_mfma_f32_16x16x32_bf16(a, b, acc[nt], 0, 0, 0);
        }
    }
    #pragma unroll
    for (int nt = 0; nt < 4; ++nt) {
        float bb1 = b1[nt * 16 + m];
        #pragma unroll
        for (int r = 0; r < 4; ++r) {
            float tv = fmaxf(acc[nt][r] + bb1, 0.f);
            tls[w][g * 4 + r][nt * 16 + m] = f2bf(tv);
        }
    }
    f32x4 acc2[4] = {{0,0,0,0},{0,0,0,0},{0,0,0,0},{0,0,0,0}};
    #pragma unroll
    for (int kb = 0; kb < 2; ++kb) {
        bf16x8 a2 = *(const bf16x8*)&tls[w][m][kb * 32 + g * 8];
        #pragma unroll
        for (int nt = 0; nt < 4; ++nt) {
            bf16x8 b = *(const bf16x8*)(w2f + (((size_t)nt * 2 + kb) * 64 + lane) * 8);
            acc2[nt] = __builtin_amdgcn_mfma_f32_16x16x32_bf16(a2, b, acc2[nt], 0, 0, 0);
        }
    }
    // h store + bf16 h into ahb + tls (for proj A-fragments)
    #pragma unroll
    for (int nt = 0; nt < 4; ++nt) {
        float bb2 = b2[nt * 16 + m];
        #pragma unroll
        for (int r = 0; r < 4; ++r) {
            float hv = fmaxf(acc2[nt][r] + bb2, 0.f);
            int grow = rbase + w * 16 + g * 4 + r;
            ushort_t hb = f2bf(hv);
            tls[w][g * 4 + r][nt * 16 + m] = hb;
            if (grow < N) {
                h[(size_t)grow * 64 + nt * 16 + m] = hv;
                ahb[(size_t)grow * 128 + 64 + nt * 16 + m] = hb;
            }
        }
    }
    // layer-0 gate projection: [a|b] = h @ gw1
    f32x4 accp[8] = {{0,0,0,0},{0,0,0,0},{0,0,0,0},{0,0,0,0},
                     {0,0,0,0},{0,0,0,0},{0,0,0,0},{0,0,0,0}};
    #pragma unroll
    for (int kb = 0; kb < 2; ++kb) {
        bf16x8 a3 = *(const bf16x8*)&tls[w][m][kb * 32 + g * 8];
        #pragma unroll
        for (int j = 0; j < 8; ++j) {
            bf16x8 b = *(const bf16x8*)(g1f + (((size_t)j * 2 + kb) * 64 + lane) * 8);
            accp[j] = __builtin_amdgcn_mfma_f32_16x16x32_bf16(a3, b, accp[j], 0, 0, 0);
        }
    }
    #pragma unroll
    for (int nt = 0; nt < 4; ++nt) {
        float gbl = gb1[nt * 16 + m];
        #pragma unroll
        for (int r = 0; r < 4; ++r) {
            int grow = rbase + w * 16 + g * 4 + r;
            if (grow < N) {
                ahb[(size_t)grow * 128 + nt * 16 + m] = f2bf(accp[nt][r] + gbl);
                bbuf[(size_t)grow * 64 + nt * 16 + m] = accp[nt + 4][r];
            }
        }
    }
}

// ---- CSR build ----
// hist + per-edge rank (prefix within dst bucket)
__global__ __launch_bounds__(256) void hist_kernel(
    const int* __restrict__ dst, int* __restrict__ cnt,
    int* __restrict__ rank, int E) {
    for (int e = blockIdx.x * blockDim.x + threadIdx.x; e < E;
         e += gridDim.x * blockDim.x)
        rank[e] = atomicAdd(&cnt[dst[e]], 1);
}

__global__ __launch_bounds__(256) void scan1_kernel(
    const int* __restrict__ cnt, int* __restrict__ bsum, int N) {
    __shared__ int red[256];
    int i = blockIdx.x * 256 + threadIdx.x;
    red[threadIdx.x] = (i < N) ? cnt[i] : 0;
    __syncthreads();
    for (int off = 128; off > 0; off >>= 1) {
        if (threadIdx.x < off) red[threadIdx.x] += red[threadIdx.x + off];
        __syncthreads();
    }
    if (threadIdx.x == 0) bsum[blockIdx.x] = red[0];
}

__global__ __launch_bounds__(1024) void scan2_kernel(
    int* __restrict__ bsum, int nb) {
    __shared__ int s[1024];
    int v = (threadIdx.x < nb) ? bsum[threadIdx.x] : 0;
    s[threadIdx.x] = v;
    __syncthreads();
    for (int off = 1; off < 1024; off <<= 1) {
        int t = (threadIdx.x >= off) ? s[threadIdx.x - off] : 0;
        __syncthreads();
        s[threadIdx.x] += t;
        __syncthreads();
    }
    if (threadIdx.x < nb) bsum[threadIdx.x] = s[threadIdx.x] - v;  // exclusive
}

__global__ __launch_bounds__(256) void scan3_kernel(
    const int* __restrict__ cnt, const int* __restrict__ bsum,
    int* __restrict__ row_ptr, int N) {
    __shared__ int s[256];
    int i = blockIdx.x * 256 + threadIdx.x;
    int v = (i < N) ? cnt[i] : 0;
    s[threadIdx.x] = v;
    __syncthreads();
    for (int off = 1; off < 256; off <<= 1) {
        int t = (threadIdx.x >= off) ? s[threadIdx.x - off] : 0;
        __syncthreads();
        s[threadIdx.x] += t;
        __syncthreads();
    }
    if (i < N) row_ptr[i] = bsum[blockIdx.x] + s[threadIdx.x] - v;  // exclusive
    if (i == N - 1) row_ptr[N] = bsum[blockIdx.x] + s[threadIdx.x]; // total
}

// atomic-free scatter: pos = row_ptr[dst] + rank (precomputed in hist)
__global__ __launch_bounds__(256) void scatter_kernel(
    const int* __restrict__ src, const int* __restrict__ dst,
    const float* __restrict__ base_w, const float* __restrict__ rr,
    const int* __restrict__ row_ptr, const int* __restrict__ rank,
    int2* __restrict__ recs, int E) {
    for (int e = blockIdx.x * blockDim.x + threadIdx.x; e < E;
         e += gridDim.x * blockDim.x) {
        int s = src[e], d = dst[e];
        int pos = row_ptr[d] + rank[e];
        float rs = 1.f / (1.f + __expf(-rr[s]));
        float rd = 1.f / (1.f + __expf(-rr[d]));
        float c = base_w[e] * rs * rd;
        recs[pos] = make_int2(s, __float_as_int(c));
    }
}

// fused gate + aggregation (R12, proven): wave-per-node, 16-lane group/edge.
__global__ __launch_bounds__(256) void gateagg_kernel(
    const int* __restrict__ row_ptr, const int2* __restrict__ recs,
    const ushort_t* __restrict__ ahb, const float* __restrict__ bb,
    const float* __restrict__ gw2, const float* __restrict__ gb2,
    float* __restrict__ m, float* __restrict__ deg, int N) {
    const int lane = threadIdx.x & 63;
    const int sub  = lane & 15;
    const int grp  = lane >> 4;
    const float4 gv = ((const float4*)gw2)[sub];
    const float gb = gb2[0];
    const int wid  = blockIdx.x * (blockDim.x >> 6) + (threadIdx.x >> 6);
    const int nw   = gridDim.x * (blockDim.x >> 6);
    for (int n = wid; n < N; n += nw) {
        const int beg = row_ptr[n], end = row_ptr[n + 1];
        const float4 bv = *(const float4*)(bb + (size_t)n * 64 + sub * 4);
        float m0 = 0.f, m1 = 0.f, m2 = 0.f, m3 = 0.f, dacc = 0.f;
        int i = beg + grp;
        for (; i + 4 < end; i += 8) {
            int2 rA = recs[i];
            int2 rB = recs[i + 4];
            const ushort_t* rowA = ahb + (size_t)rA.x * 128;
            const ushort_t* rowB = ahb + (size_t)rB.x * 128;
            ushort4 avA = *(const ushort4*)(rowA + sub * 4);
            ushort4 hvA = *(const ushort4*)(rowA + 64 + sub * 4);
            ushort4 avB = *(const ushort4*)(rowB + sub * 4);
            ushort4 hvB = *(const ushort4*)(rowB + 64 + sub * 4);
            float tA = fmaxf(bf2f(avA.x) + bv.x, 0.f) * gv.x
                     + fmaxf(bf2f(avA.y) + bv.y, 0.f) * gv.y
                     + fmaxf(bf2f(avA.z) + bv.z, 0.f) * gv.z
                     + fmaxf(bf2f(avA.w) + bv.w, 0.f) * gv.w;
            float tB = fmaxf(bf2f(avB.x) + bv.x, 0.f) * gv.x
                     + fmaxf(bf2f(avB.y) + bv.y, 0.f) * gv.y
                     + fmaxf(bf2f(avB.z) + bv.z, 0.f) * gv.z
                     + fmaxf(bf2f(avB.w) + bv.w, 0.f) * gv.w;
            #pragma unroll
            for (int o = 8; o > 0; o >>= 1) {
                tA += __shfl_xor(tA, o, 64);
                tB += __shfl_xor(tB, o, 64);
            }
            float wA = __int_as_float(rA.y) / (1.f + __expf(-(tA + gb)));
            float wB = __int_as_float(rB.y) / (1.f + __expf(-(tB + gb)));
            m0 = fmaf(wA, bf2f(hvA.x), m0); m0 = fmaf(wB, bf2f(hvB.x), m0);
            m1 = fmaf(wA, bf2f(hvA.y), m1); m1 = fmaf(wB, bf2f(hvB.y), m1);
            m2 = fmaf(wA, bf2f(hvA.z), m2); m2 = fmaf(wB, bf2f(hvB.z), m2);
            m3 = fmaf(wA, bf2f(hvA.w), m3); m3 = fmaf(wB, bf2f(hvB.w), m3);
            dacc += wA + wB;
        }
        if (i < end) {
            int2 r = recs[i];
            const ushort_t* row = ahb + (size_t)r.x * 128;
            ushort4 av = *(const ushort4*)(row + sub * 4);
            ushort4 hv = *(const ushort4*)(row + 64 + sub * 4);
            float t = fmaxf(bf2f(av.x) + bv.x, 0.f) * gv.x
                    + fmaxf(bf2f(av.y) + bv.y, 0.f) * gv.y
                    + fmaxf(bf2f(av.z) + bv.z, 0.f) * gv.z
                    + fmaxf(bf2f(av.w) + bv.w, 0.f) * gv.w;
            #pragma unroll
            for (int o = 8; o > 0; o >>= 1) t += __shfl_xor(t, o, 64);
            float w = __int_as_float(r.y) / (1.f + __expf(-(t + gb)));
            m0 = fmaf(w, bf2f(hv.x), m0);
            m1 = fmaf(w, bf2f(hv.y), m1);
            m2 = fmaf(w, bf2f(hv.z), m2);
            m3 = fmaf(w, bf2f(hv.w), m3);
            dacc += w;
        }
        #pragma unroll
        for (int o = 16; o < 64; o <<= 1) {
            m0 += __shfl_xor(m0, o, 64);
            m1 += __shfl_xor(m1, o, 64);
            m2 += __shfl_xor(m2, o, 64);
            m3 += __shfl_xor(m3, o, 64);
            dacc += __shfl_xor(dacc, o, 64);
        }
        if (lane < 16) {
            *(float4*)(m + (size_t)n * 64 + sub * 4) = make_float4(m0, m1, m2, m3);
            if (lane == 0) deg[n] = dacc;
        }
    }
}

// MFMA update + residual + LayerNorm, with fused epilogue:
// MODE 0: gate projection for the next layer (ahb/bbuf) + h_out store.
// MODE 1: softplus output head (U = softplus(h@toU_w+toU_b)), no h_out.
template <int MODE>
__global__ __launch_bounds__(256) void upd_kernel(
    const float* __restrict__ m, const float* __restrict__ deg,
    const float* __restrict__ h_in,
    const ushort_t* __restrict__ u1f, const float* __restrict__ b1,
    const ushort_t* __restrict__ u2f, const float* __restrict__ b2,
    const float* __restrict__ lng, const float* __restrict__ lnb,
    const ushort_t* __restrict__ g1f, const float* __restrict__ gb1,
    ushort_t* __restrict__ ahb, float* __restrict__ bbuf,
    const ushort_t* __restrict__ tuf, const float* __restrict__ tub,
    float* __restrict__ h_out, float* __restrict__ U, int N) {
    __shared__ ushort_t mls[4][16][72];
    __shared__ ushort_t tls[4][16][72];
    const int tid  = threadIdx.x;
    const int lane = tid & 63;
    const int w    = tid >> 6;
    const int m_   = lane & 15;
    const int g    = lane >> 4;
    const int rbase = blockIdx.x * 64;
    for (int p = tid; p < 64 * 32; p += 256) {
        int row = p >> 5, c2 = p & 31;
        int grow = rbase + row;
        float2 v = make_float2(0.f, 0.f);
        if (grow < N) {
            float dg = deg[grow] + 1e-8f;
            float2 mv = *(const float2*)(m + (size_t)grow * 64 + c2 * 2);
            v = make_float2(mv.x / dg, mv.y / dg);
        }
        unsigned int pk = (unsigned int)f2bf(v.x) | ((unsigned int)f2bf(v.y) << 16);
        *(unsigned int*)&mls[row >> 4][row & 15][c2 * 2] = pk;
    }
    __syncthreads();
    f32x4 acc[4] = {{0,0,0,0},{0,0,0,0},{0,0,0,0},{0,0,0,0}};
    #pragma unroll
    for (int kb = 0; kb < 2; ++kb) {
        bf16x8 a = *(const bf16x8*)&mls[w][m_][kb * 32 + g * 8];
        #pragma unroll
        for (int nt = 0; nt < 4; ++nt) {
            bf16x8 b = *(const bf16x8*)(u1f + (((size_t)nt * 2 + kb) * 64 + lane) * 8);
            acc[nt] = __builtin_amdgcn_mfma_f32_16x16x32_bf16(a, b, acc[nt], 0, 0, 0);
        }
    }
    #pragma unroll
    for (int nt = 0; nt < 4; ++nt) {
        float bb1 = b1[nt * 16 + m_];
        #pragma unroll
        for (int r = 0; r < 4; ++r)
            tls[w][g * 4 + r][nt * 16 + m_] = f2bf(fmaxf(acc[nt][r] + bb1, 0.f));
    }
    f32x4 acc2[4] = {{0,0,0,0},{0,0,0,0},{0,0,0,0},{0,0,0,0}};
    #pragma unroll
    for (int kb = 0; kb < 2; ++kb) {
        bf16x8 a2 = *(const bf16x8*)&tls[w][m_][kb * 32 + g * 8];
        #pragma unroll
        for (int nt = 0; nt < 4; ++nt) {
            bf16x8 b = *(const bf16x8*)(u2f + (((size_t)nt * 2 + kb) * 64 + lane) * 8);
            acc2[nt] = __builtin_amdgcn_mfma_f32_16x16x32_bf16(a2, b, acc2[nt], 0, 0, 0);
        }
    }
    // residual + LN (in D-layout), write hn to tls for epilogue A-fragments
    float hn_reg[4][4];   // [r][nt]
    #pragma unroll
    for (int r = 0; r < 4; ++r) {
        const int grow = rbase + w * 16 + g * 4 + r;
        float pre[4];
        float s1 = 0.f, s2 = 0.f;
        #pragma unroll
        for (int nt = 0; nt < 4; ++nt) {
            float hv = (grow < N) ? h_in[(size_t)grow * 64 + nt * 16 + m_] : 0.f;
            pre[nt] = acc2[nt][r] + b2[nt * 16 + m_] + hv;
            s1 += pre[nt];
            s2 += pre[nt] * pre[nt];
        }
        #pragma unroll
        for (int o = 1; o < 16; o <<= 1) {
            s1 += __shfl_xor(s1, o, 64);
            s2 += __shfl_xor(s2, o, 64);
        }
        float mean = s1 * (1.0f / 64.0f);
        float var  = s2 * (1.0f / 64.0f) - mean * mean;
        float rinv = rsqrtf(var + 1e-5f);
        #pragma unroll
        for (int nt = 0; nt < 4; ++nt) {
            float hn = (pre[nt] - mean) * rinv * lng[nt * 16 + m_] + lnb[nt * 16 + m_];
            hn_reg[r][nt] = hn;
            tls[w][g * 4 + r][nt * 16 + m_] = f2bf(hn);
        }
    }
    if (MODE == 0) {
        // h_out + bf16 h into ahb
        #pragma unroll
        for (int nt = 0; nt < 4; ++nt) {
            #pragma unroll
            for (int r = 0; r < 4; ++r) {
                int grow = rbase + w * 16 + g * 4 + r;
                if (grow < N) {
                    h_out[(size_t)grow * 64 + nt * 16 + m_] = hn_reg[r][nt];
                    ahb[(size_t)grow * 128 + 64 + nt * 16 + m_] = f2bf(hn_reg[r][nt]);
                }
            }
        }
        // gate projection for next layer
        f32x4 accp[8] = {{0,0,0,0},{0,0,0,0},{0,0,0,0},{0,0,0,0},
                         {0,0,0,0},{0,0,0,0},{0,0,0,0},{0,0,0,0}};
        #pragma unroll
        for (int kb = 0; kb < 2; ++kb) {
            bf16x8 a3 = *(const bf16x8*)&tls[w][m_][kb * 32 + g * 8];
            #pragma unroll
            for (int j = 0; j < 8; ++j) {
                bf16x8 b = *(const bf16x8*)(g1f + (((size_t)j * 2 + kb) * 64 + lane) * 8);
                accp[j] = __builtin_amdgcn_mfma_f32_16x16x32_bf16(a3, b, accp[j], 0, 0, 0);
            }
        }
        #pragma unroll
        for (int nt = 0; nt < 4; ++nt) {
            float gbl = gb1[nt * 16 + m_];
            #pragma unroll
            for (int r = 0; r < 4; ++r) {
                int grow = rbase + w * 16 + g * 4 + r;
                if (grow < N) {
                    ahb[(size_t)grow * 128 + nt * 16 + m_] = f2bf(accp[nt][r] + gbl);
                    bbuf[(size_t)grow * 64 + nt * 16 + m_] = accp[nt + 4][r];
                }
            }
        }
    } else {
        // output head: U = softplus(h @ toU_w + toU_b), K = 32 (2 nt tiles)
        f32x4 accu[2] = {{0,0,0,0},{0,0,0,0}};
        #pragma unroll
        for (int kb = 0; kb < 2; ++kb) {
            bf16x8 a3 = *(const bf16x8*)&tls[w][m_][kb * 32 + g * 8];
            #pragma unroll
            for (int nt = 0; nt < 2; ++nt) {
                bf16x8 b = *(const bf16x8*)(tuf + (((size_t)nt * 2 + kb) * 64 + lane) * 8);
                accu[nt] = __builtin_amdgcn_mfma_f32_16x16x32_bf16(a3, b, accu[nt], 0, 0, 0);
            }
        }
        #pragma unroll
        for (int nt = 0; nt < 2; ++nt) {
            float tb = tub[nt * 16 + m_];
            #pragma unroll
            for (int r = 0; r < 4; ++r) {
                int grow = rbase + w * 16 + g * 4 + r;
                if (grow < N) {
                    float av = accu[nt][r] + tb;
                    float sp = av > 0.f ? av + log1pf(__expf(-av))
                                        : log1pf(__expf(av));
                    U[(size_t)grow * 32 + nt * 16 + m_] = sp;
                }
            }
        }
    }
}

extern "C" void kernel_launch(void* const* d_in, const int* in_sizes, int n_in,
                              void* d_out, int out_size, void* d_ws, size_t ws_size,
                              hipStream_t stream) {
    const float* x       = (const float*)d_in[0];
    const int*   src     = (const int*)d_in[1];
    const int*   dst     = (const int*)d_in[2];
    const float* base_w  = (const float*)d_in[3];
    const float* enc_w1  = (const float*)d_in[4];
    const float* enc_b1  = (const float*)d_in[5];
    const float* enc_w2  = (const float*)d_in[6];
    const float* enc_b2  = (const float*)d_in[7];
    const float* gate_w1 = (const float*)d_in[8];
    const float* gate_b1 = (const float*)d_in[9];
    const float* gate_w2 = (const float*)d_in[10];
    const float* gate_b2 = (const float*)d_in[11];
    const float* upd_w1  = (const float*)d_in[12];
    const float* upd_b1  = (const float*)d_in[13];
    const float* upd_w2  = (const float*)d_in[14];
    const float* upd_b2  = (const float*)d_in[15];
    const float* ln_g    = (const float*)d_in[16];
    const float* ln_b    = (const float*)d_in[17];
    const float* rho_raw = (const float*)d_in[18];
    const float* toU_w   = (const float*)d_in[19];
    const float* toU_b   = (const float*)d_in[20];

    const int N = in_sizes[18];          // 50000
    const int E = in_sizes[1];           // 800000
    const int nsb = (N + 255) / 256;     // scan blocks

    // workspace layout (float units)
    float* ws  = (float*)d_ws;
    size_t off = 0;
    float* h0  = ws + off; off += (size_t)N * 64;
    float* h1  = ws + off; off += (size_t)N * 64;
    ushort_t* ahb = (ushort_t*)(ws + off); off += (size_t)N * 64;  // N*128 ushort
    float* bb  = ws + off; off += (size_t)N * 64;
    float* m   = ws + off; off += (size_t)N * 64;
    float* deg = ws + off; off += (size_t)((N + 3) & ~3);
    int* row_ptr = (int*)(ws + off); off += (size_t)((N + 1 + 3) & ~3);
    int* cnt     = (int*)(ws + off); off += (size_t)((N + 3) & ~3);
    int* bsum    = (int*)(ws + off); off += (size_t)((nsb + 3) & ~3);
    int* rank    = (int*)(ws + off); off += (size_t)E;
    int2* recs   = (int2*)(ws + off); off += (size_t)E * 2;   // (s,c)
    ushort_t* w1f = (ushort_t*)(ws + off); off += 8192;       // 16384 ushort
    ushort_t* w2f = (ushort_t*)(ws + off); off += 2048;       // 4096 ushort
    ushort_t* g1f = (ushort_t*)(ws + off); off += 4096;       // 8192 ushort
    ushort_t* u1f = (ushort_t*)(ws + off); off += 4096;       // 8192 ushort
    ushort_t* u2f = (ushort_t*)(ws + off); off += 4096;       // 8192 ushort
    ushort_t* tuf = (ushort_t*)(ws + off); off += 1024;       // 2048 ushort

    pack_kernel<<<64, 256, 0, stream>>>(enc_w1, enc_w2, gate_w1, upd_w1, upd_w2,
                                        toU_w, w1f, w2f, g1f, u1f, u2f, tuf);
    const int nblk64 = (N + 63) / 64;
    enc_kernel<<<nblk64, 256, 0, stream>>>(x, w1f, enc_b1, w2f, enc_b2,
                                           g1f, gate_b1, h0, ahb, bb, N);

    // CSR build: rank-hist -> hierarchical scan -> atomic-free scatter
    hipMemsetAsync(cnt, 0, (size_t)N * sizeof(int), stream);
    hist_kernel<<<(E + 255) / 256, 256, 0, stream>>>(dst, cnt, rank, E);
    scan1_kernel<<<nsb, 256, 0, stream>>>(cnt, bsum, N);
    scan2_kernel<<<1, 1024, 0, stream>>>(bsum, nsb);
    scan3_kernel<<<nsb, 256, 0, stream>>>(cnt, bsum, row_ptr, N);
    scatter_kernel<<<(E + 255) / 256, 256, 0, stream>>>(src, dst, base_w, rho_raw,
                                                        row_ptr, rank, recs, E);

    // layer 0: gateagg -> upd<0> (proj for layer 1)
    gateagg_kernel<<<2048, 256, 0, stream>>>(row_ptr, recs, ahb, bb,
                                             gate_w2, gate_b2, m, deg, N);
    upd_kernel<0><<<nblk64, 256, 0, stream>>>(
        m, deg, h0, u1f, upd_b1, u2f, upd_b2, ln_g, ln_b,
        g1f, gate_b1, ahb, bb, tuf, toU_b, h1, (float*)d_out, N);

    // layer 1: gateagg -> upd<1> (softplus head -> d_out)
    gateagg_kernel<<<2048, 256, 0, stream>>>(row_ptr, recs, ahb, bb,
                                             gate_w2, gate_b2, m, deg, N);
    upd_kernel<1><<<nblk64, 256, 0, stream>>>(
        m, deg, h1, u1f + 4096, upd_b1 + 64, u2f + 4096, upd_b2 + 64,
        ln_g + 64, ln_b + 64,
        g1f, gate_b1, ahb, bb, tuf, toU_b, nullptr, (float*)d_out, N);
}